// Round 13
// baseline (132.858 us; speedup 1.0000x reference)
//
#include <hip/hip_runtime.h>
#include <hip/hip_bf16.h>
#include <stdint.h>

#define NBS 2
#define SEQ 2048
#define DMODEL 1024
#define NH 16
#define DHEAD 64
#define MROWS (NBS*SEQ)     // 4096
#define NQKV (NH*3*DHEAD)   // 3072

typedef __bf16 bf16;
typedef __bf16 bf16x8 __attribute__((ext_vector_type(8)));
typedef float f32x4 __attribute__((ext_vector_type(4)));
typedef float f32x16 __attribute__((ext_vector_type(16)));
typedef unsigned int u32x2 __attribute__((ext_vector_type(2)));

#define LOG2E 1.44269504088896f
#define QSCALE (0.125f * LOG2E)

static __device__ __forceinline__ void gload_lds16(const bf16* g, bf16* l) {
    __builtin_amdgcn_global_load_lds(
        (const __attribute__((address_space(1))) uint32_t*)g,
        (__attribute__((address_space(3))) uint32_t*)l, 16, 0, 0);
}

static __device__ __forceinline__ bf16x8 ld_b8(const bf16* p) {
    return __builtin_bit_cast(bf16x8, *(const uint4*)p);
}

static __device__ __forceinline__ uint32_t pk_bf16(float lo, float hi) {
    unsigned short l = __builtin_bit_cast(unsigned short, (bf16)lo);
    unsigned short h = __builtin_bit_cast(unsigned short, (bf16)hi);
    return ((uint32_t)h << 16) | (uint32_t)l;
}

static __device__ __forceinline__ u32x2 lane_swap32(uint32_t a, uint32_t b, int lane) {
#if __has_builtin(__builtin_amdgcn_permlane32_swap)
    return __builtin_amdgcn_permlane32_swap(a, b, false, false);
#else
    uint32_t sa = __shfl_xor(a, 32), sb = __shfl_xor(b, 32);
    u32x2 r;
    r.x = (lane >= 32) ? sb : a;
    r.y = (lane >= 32) ? b : sa;
    return r;
#endif
}

// ---------------- convert kernels ----------------

__global__ void k_cvt(const float* __restrict__ in, bf16* __restrict__ out, int n4) {
    int i = blockIdx.x * blockDim.x + threadIdx.x;
    if (i < n4) {
        float4 v = ((const float4*)in)[i];
        ushort4 o;
        o.x = __builtin_bit_cast(unsigned short, (bf16)v.x);
        o.y = __builtin_bit_cast(unsigned short, (bf16)v.y);
        o.z = __builtin_bit_cast(unsigned short, (bf16)v.z);
        o.w = __builtin_bit_cast(unsigned short, (bf16)v.w);
        ((ushort4*)out)[i] = o;
    }
}

// in: [R][C] f32 row-major -> out: [C][R] bf16 (B^T for GEMM)
__global__ void k_tcvt(const float* __restrict__ in, bf16* __restrict__ out, int R, int C) {
    __shared__ float t[32][33];
    int tx = threadIdx.x, ty = threadIdx.y;   // 32 x 8
    int r0 = blockIdx.y * 32, c0 = blockIdx.x * 32;
#pragma unroll
    for (int i = 0; i < 4; i++)
        t[ty + i*8][tx] = in[(size_t)(r0 + ty + i*8) * C + (c0 + tx)];
    __syncthreads();
#pragma unroll
    for (int i = 0; i < 4; i++)
        out[(size_t)(c0 + ty + i*8) * R + (r0 + tx)] = (bf16)t[tx][ty + i*8];
}

// w_qkv variant with column permute: col(h*192+kind*64+d) -> kind*1024+h*64+d.
__global__ void k_tcvt_qkv(const float* __restrict__ in, bf16* __restrict__ out) {
    __shared__ float t[32][33];
    int tx = threadIdx.x, ty = threadIdx.y;   // 32 x 8
    int r0 = blockIdx.y * 32, c0 = blockIdx.x * 32;
#pragma unroll
    for (int i = 0; i < 4; i++)
        t[ty + i*8][tx] = in[(size_t)(r0 + ty + i*8) * NQKV + (c0 + tx)];
    __syncthreads();
#pragma unroll
    for (int i = 0; i < 4; i++) {
        int c = c0 + ty + i*8;
        int h = c / 192, f = c % 192;
        int cperm = ((f >> 6) << 10) + (h << 6) + (f & 63);
        out[(size_t)cperm * DMODEL + (r0 + tx)] = (bf16)t[tx][ty + i*8];
    }
}

// ---------------- GEMM1: 256x256 tile, BK=64, 512 thr, counted-vmcnt pipeline --
#define G1_NT 16   // 1024/64 K-tiles

__global__ __launch_bounds__(512, 2) void k_gemm_qkv(
        const bf16* __restrict__ A, const bf16* __restrict__ Bt,
        const float* __restrict__ bias,
        bf16* __restrict__ Q, bf16* __restrict__ Kp, bf16* __restrict__ Vt) {
    __shared__ __align__(16) bf16 As[2][256*64];
    __shared__ __align__(16) bf16 Bs[2][256*64];
    int tid = threadIdx.x;
    int wid = tid >> 6, lane = tid & 63;
    int wr = wid >> 2, wc = wid & 3;
    int g = lane >> 4, r = lane & 15;

    int lid = blockIdx.y * 12 + blockIdx.x;
    int swz = (lid & 7) * 24 + (lid >> 3);
    int tile_n = (swz % 12) * 256, tile_m = (swz / 12) * 256;

    f32x4 acc[8][4];
#pragma unroll
    for (int m = 0; m < 8; m++)
#pragma unroll
        for (int n = 0; n < 4; n++)
            acc[m][n] = (f32x4){0.f, 0.f, 0.f, 0.f};

    int srow[4], schk[4];
#pragma unroll
    for (int j2 = 0; j2 < 4; j2++) {
        int idx = tid + j2 * 512;
        srow[j2] = idx >> 3;
        schk[j2] = ((idx & 7) ^ (srow[j2] & 7)) * 8;
    }

#define G1_STAGE(buf, k0)                                                        \
    {                                                                            \
        _Pragma("unroll")                                                        \
        for (int j2 = 0; j2 < 4; j2++) {                                         \
            gload_lds16(A  + (size_t)(tile_m + srow[j2]) * DMODEL + (k0) + schk[j2], \
                        As[buf] + (tid + j2*512) * 8);                           \
            gload_lds16(Bt + (size_t)(tile_n + srow[j2]) * DMODEL + (k0) + schk[j2], \
                        Bs[buf] + (tid + j2*512) * 8);                           \
        }                                                                        \
    }

    G1_STAGE(0, 0);

    int r7 = r & 7;
    for (int t = 0; t < G1_NT; t++) {
        int cur = t & 1;
        if (t + 1 < G1_NT) {
            G1_STAGE(cur ^ 1, (t + 1) * 64);
            asm volatile("s_waitcnt vmcnt(8)" ::: "memory");
        } else {
            asm volatile("s_waitcnt vmcnt(0)" ::: "memory");
        }
        __builtin_amdgcn_s_barrier();
        __builtin_amdgcn_sched_barrier(0);

        const bf16* pa = As[cur];
        const bf16* pb = Bs[cur];
#pragma unroll
        for (int kk = 0; kk < 2; kk++) {
            int rchk = ((kk*4 + g) ^ r7) * 8;
            bf16x8 bfr[4];
#pragma unroll
            for (int n = 0; n < 4; n++)
                bfr[n] = ld_b8(pb + (wc*64 + n*16 + r) * 64 + rchk);
#pragma unroll
            for (int m = 0; m < 8; m++) {
                bf16x8 af = ld_b8(pa + (wr*128 + m*16 + r) * 64 + rchk);
#pragma unroll
                for (int n = 0; n < 4; n++)
                    acc[m][n] = __builtin_amdgcn_mfma_f32_16x16x32_bf16(af, bfr[n], acc[m][n], 0, 0, 0);
            }
        }
        asm volatile("s_waitcnt lgkmcnt(0)" ::: "memory");
        __builtin_amdgcn_s_barrier();
    }

#pragma unroll
    for (int m = 0; m < 8; m++) {
#pragma unroll
        for (int n = 0; n < 4; n++) {
            int col = tile_n + wc*64 + n*16 + r;
            int kind = col >> 10;
            int h = (col >> 6) & 15;
            int d = col & 63;
            float bv = bias[h*192 + (kind << 6) + d];
            if (kind == 2) {
                int row0 = tile_m + wr*128 + m*16 + g*4;
                int b = row0 >> 11, s0 = row0 & 2047;
                ushort4 vv;
                vv.x = __builtin_bit_cast(unsigned short, (bf16)(acc[m][n][0] + bv));
                vv.y = __builtin_bit_cast(unsigned short, (bf16)(acc[m][n][1] + bv));
                vv.z = __builtin_bit_cast(unsigned short, (bf16)(acc[m][n][2] + bv));
                vv.w = __builtin_bit_cast(unsigned short, (bf16)(acc[m][n][3] + bv));
                *(ushort4*)&Vt[(((size_t)(b*NH + h)) * DHEAD + d) * SEQ + s0] = vv;
            } else {
#pragma unroll
                for (int j = 0; j < 4; j++) {
                    int row = tile_m + wr*128 + m*16 + g*4 + j;
                    int b = row >> 11, s = row & 2047;
                    float v = acc[m][n][j] + bv;
                    size_t addr = (((size_t)(b*NH + h)) * SEQ + s) * DHEAD + d;
                    if (kind == 0) Q[addr]  = (bf16)(v * QSCALE);
                    else           Kp[addr] = (bf16)v;
                }
            }
        }
    }
#undef G1_STAGE
}

// ---- gemm_out: 64x128 tile, 4 waves, 2-barrier, grid 512 ----
__global__ __launch_bounds__(256) void k_gemm_out(
        const bf16* __restrict__ A, const bf16* __restrict__ Bt,
        const float* __restrict__ bias, float* __restrict__ out) {
    __shared__ __align__(16) bf16 As[64*32];
    __shared__ __align__(16) bf16 Bs[128*32];
    int tid = threadIdx.x;
    int wave = tid >> 6, lane = tid & 63;
    int g = lane >> 4, r = lane & 15;
    int srow = lane >> 2, schunk = (lane & 3) * 8;
    int tile_m = blockIdx.y * 64, tile_n = blockIdx.x * 128;

    f32x4 acc[4][2];
#pragma unroll
    for (int m = 0; m < 4; m++)
#pragma unroll
        for (int n = 0; n < 2; n++)
            acc[m][n] = (f32x4){0.f, 0.f, 0.f, 0.f};

    for (int k0 = 0; k0 < DMODEL; k0 += 32) {
        gload_lds16(A  + (size_t)(tile_m + wave*16 + srow) * DMODEL + k0 + schunk, As + wave*512);
        gload_lds16(Bt + (size_t)(tile_n + wave*16 + srow) * DMODEL + k0 + schunk, Bs + wave*512);
        gload_lds16(Bt + (size_t)(tile_n + 64 + wave*16 + srow) * DMODEL + k0 + schunk, Bs + 2048 + wave*512);
        __syncthreads();
        bf16x8 af[4], bfr[2];
#pragma unroll
        for (int m = 0; m < 4; m++) af[m]  = *(const bf16x8*)(As + (m*16 + r)*32 + g*8);
#pragma unroll
        for (int n = 0; n < 2; n++) bfr[n] = *(const bf16x8*)(Bs + (wave*32 + n*16 + r)*32 + g*8);
#pragma unroll
        for (int m = 0; m < 4; m++)
#pragma unroll
            for (int n = 0; n < 2; n++)
                acc[m][n] = __builtin_amdgcn_mfma_f32_16x16x32_bf16(af[m], bfr[n], acc[m][n], 0, 0, 0);
        __syncthreads();
    }

#pragma unroll
    for (int m = 0; m < 4; m++) {
#pragma unroll
        for (int n = 0; n < 2; n++) {
            int col = tile_n + wave*32 + n*16 + r;
            float bv = bias[col];
#pragma unroll
            for (int j = 0; j < 4; j++) {
                int row = tile_m + m*16 + g*4 + j;
                out[(size_t)row * DMODEL + col] = acc[m][n][j] + bv;
            }
        }
    }
}

// ---------------- flash attention v6: pair-tile phases, gload_lds staging ----
// K in LDS [128][64] (XOR chunk^(row&7)), V^T in LDS [64][128] (same XOR).
// One barrier phase stages 2 KV tiles; compute QK(a);QK(b);rest(a);rest(b)
// in one region for cross-tile ILP. V-frags loaded JIT inside PV.
#define QBLK 128
#define KVB 64

static __device__ __forceinline__ void a_qk(
        const bf16* KsL, const bf16x8 qa2[4], f32x16 st[2], int s, int l31, int hi) {
    int sw = (l31 & 7) << 3;
    __builtin_amdgcn_s_setprio(1);
#pragma unroll
    for (int rb = 0; rb < 2; rb++)
#pragma unroll
        for (int c = 0; c < 4; c++) {
            bf16x8 kf = ld_b8(KsL + (s*64 + rb*32 + l31)*64 + ((c*16 + hi*8) ^ sw));
            st[rb] = __builtin_amdgcn_mfma_f32_32x32x16_bf16(kf, qa2[c], st[rb], 0, 0, 0);
        }
    __builtin_amdgcn_s_setprio(0);
}

static __device__ __forceinline__ void a_rest(
        const bf16* VsL, f32x16 st[2], const bf16x8& ones,
        f32x16 o32[2], f32x16& acc_l,
        int s, int kvb, int qb, int qrow, int l31, int hi, int lane) {
    bool needm = (kvb + KVB - 1) > qb;
    if (needm) {
#pragma unroll
        for (int rb = 0; rb < 2; rb++)
#pragma unroll
            for (int reg = 0; reg < 16; reg++) {
                float e = __builtin_amdgcn_exp2f(st[rb][reg]);
                int kv = kvb + rb*32 + (reg & 3) + 8*(reg >> 2) + 4*hi;
                if (kv > qrow) e = 0.f;
                st[rb][reg] = e;
            }
    } else {
#pragma unroll
        for (int rb = 0; rb < 2; rb++)
#pragma unroll
            for (int reg = 0; reg < 16; reg++)
                st[rb][reg] = __builtin_amdgcn_exp2f(st[rb][reg]);
    }

    bf16x8 pa[4];
#pragma unroll
    for (int c = 0; c < 4; c++) {
        const f32x16& pp = st[c >> 1];
        const int base = (c & 1) * 8;
        uint32_t a0 = pk_bf16(pp[base+0], pp[base+1]);
        uint32_t a1 = pk_bf16(pp[base+2], pp[base+3]);
        uint32_t b0 = pk_bf16(pp[base+4], pp[base+5]);
        uint32_t b1 = pk_bf16(pp[base+6], pp[base+7]);
        u32x2 s0 = lane_swap32(a0, b0, lane);
        u32x2 s1 = lane_swap32(a1, b1, lane);
        uint4 fr = {s0.x, s1.x, s0.y, s1.y};
        pa[c] = __builtin_bit_cast(bf16x8, fr);
    }

    int sw = (l31 & 7) << 3;
    __builtin_amdgcn_s_setprio(1);
#pragma unroll
    for (int dblk = 0; dblk < 2; dblk++)
#pragma unroll
        for (int c = 0; c < 4; c++) {
            bf16x8 vf = ld_b8(VsL + (dblk*32 + l31)*128 + ((s*64 + c*16 + hi*8) ^ sw));
            o32[dblk] = __builtin_amdgcn_mfma_f32_32x32x16_bf16(pa[c], vf, o32[dblk], 0, 0, 0);
        }
#pragma unroll
    for (int c = 0; c < 4; c++)
        acc_l = __builtin_amdgcn_mfma_f32_32x32x16_bf16(pa[c], ones, acc_l, 0, 0, 0);
    __builtin_amdgcn_s_setprio(0);
}

// ---- equal-length job tables (R8) ----
__device__ const int8_t JQC[32]  = {10,10, 4, 0, 15,15, 3, 1,  9, 9, 7, 2, 13,14, 7, 5,
                                    14,14,11, 5, 15, 8,11, 6,  8,12,12, 6, 13,13,11,12};
__device__ const int8_t JT0[32]  = { 0,11, 0, 0,  0,11, 0, 0,  0,10, 0, 0,  0, 0, 8, 0,
                                    10,20, 0, 6, 22, 0, 8, 0,  9, 0, 9, 7, 10,19,16,18};
__device__ const int8_t JT1[32]  = {11,22,10, 2, 11,22, 8, 4, 10,20, 8, 6, 10,10,16, 6,
                                    20,30, 8,12, 32, 9,16, 7, 18, 9,18,14, 19,28,24,26};
__device__ const int8_t JSEG[32] = { 0, 1, 0, 0,  0, 1, 0, 0,  0, 1, 0, 0,  0, 0, 1, 0,
                                     1, 2, 0, 1,  2, 0, 1, 0,  1, 0, 1, 1,  1, 2, 2, 2};

__global__ __launch_bounds__(256, 3) void k_attn_split(
        const bf16* __restrict__ Q, const bf16* __restrict__ K,
        const bf16* __restrict__ Vt,
        bf16* __restrict__ Op0, bf16* __restrict__ Op1, bf16* __restrict__ Op2,
        float* __restrict__ Lp0, float* __restrict__ Lp1, float* __restrict__ Lp2) {
    int scu = blockIdx.x;
    int bh = scu >> 3, slot = scu & 7;
    int j = slot * 4 + blockIdx.y;
    int qc  = JQC[j];
    int t0  = JT0[j];
    int t1  = JT1[j];
    int seg = JSEG[j];
    int q0 = qc * QBLK;
    int tid = threadIdx.x, wave = tid >> 6, lane = tid & 63;
    int l31 = lane & 31, hi = lane >> 5;

    __shared__ __align__(16) bf16 KsL[128*64];   // 16KB
    __shared__ __align__(16) bf16 VsL[64*128];   // 16KB

    const bf16* Kg = K  + (size_t)bh * SEQ * DHEAD;
    const bf16* Vg = Vt + (size_t)bh * DHEAD * SEQ;

    int qb = q0 + wave * 32;
    int qrow = qb + l31;

    const bf16* qrow_p = Q + ((size_t)bh * SEQ + qrow) * DHEAD;
    bf16x8 qa2[4];
#pragma unroll
    for (int c = 0; c < 4; c++) qa2[c] = ld_b8(qrow_p + c*16 + hi*8);

    bf16x8 ones;
#pragma unroll
    for (int c = 0; c < 8; c++) ones[c] = (bf16)1.0f;

    const f32x16 z16 = {0,0,0,0,0,0,0,0,0,0,0,0,0,0,0,0};
    f32x16 o32[2], acc_l;
    o32[0] = z16; o32[1] = z16; acc_l = z16;

    int qmax_wave = qb + 31;

#define A_STAGE(kv0s)                                                     \
    {                                                                     \
        _Pragma("unroll")                                                 \
        for (int i = 0; i < 4; i++) {                                     \
            int c2 = tid + i*256;                                         \
            int krow = c2 >> 3;                                           \
            int kch = ((c2 & 7) ^ (krow & 7)) * 8;                        \
            int kgr = (kv0s) + krow; if (kgr > SEQ-1) kgr = SEQ-1;        \
            gload_lds16(Kg + (size_t)kgr * DHEAD + kch, KsL + c2*8);      \
            int vrow = c2 >> 4;                                           \
            int vch = ((c2 & 15) ^ (vrow & 7)) * 8;                       \
            int vgc = (kv0s) + vch; if (vgc > SEQ-8) vgc = SEQ-8;         \
            gload_lds16(Vg + (size_t)vrow * SEQ + vgc, VsL + c2*8);       \
        }                                                                 \
    }

    for (int t = t0; t < t1; t += 2) {
        A_STAGE(t * KVB);
        __syncthreads();
        int kv00 = t * KVB;
        bool a1 = (t + 1 < t1) && (kv00 + KVB <= qmax_wave);
        if (kv00 <= qmax_wave) {
            f32x16 sa[2];
            sa[0] = z16; sa[1] = z16;
            if (a1) {
                f32x16 sb[2];
                sb[0] = z16; sb[1] = z16;
                a_qk(KsL, qa2, sa, 0, l31, hi);
                a_qk(KsL, qa2, sb, 1, l31, hi);
                a_rest(VsL, sa, ones, o32, acc_l, 0, kv00,     qb, qrow, l31, hi, lane);
                a_rest(VsL, sb, ones, o32, acc_l, 1, kv00+KVB, qb, qrow, l31, hi, lane);
            } else {
                a_qk(KsL, qa2, sa, 0, l31, hi);
                a_rest(VsL, sa, ones, o32, acc_l, 0, kv00, qb, qrow, l31, hi, lane);
            }
        }
        __syncthreads();
    }
#undef A_STAGE

    bf16* Op; float* Lp; size_t obase; int lbase;
    if (seg == 0)      { Op = Op0; Lp = Lp0; obase = ((size_t)bh*2048 + q0) * 64;          lbase = bh*2048 + q0; }
    else if (seg == 1) { Op = Op1; Lp = Lp1; obase = ((size_t)bh*1408 + (qc-5)*128) * 64;  lbase = bh*1408 + (qc-5)*128; }
    else               { Op = Op2; Lp = Lp2; obase = ((size_t)bh*640  + (qc-11)*128) * 64; lbase = bh*640  + (qc-11)*128; }

    if (l31 == 0) {
#pragma unroll
        for (int reg = 0; reg < 16; reg++) {
            int qr = (reg & 3) + 8*(reg >> 2) + 4*hi;
            Lp[lbase + wave*32 + qr] = acc_l[reg];
        }
    }

#pragma unroll
    for (int reg = 0; reg < 16; reg++) {
        int qr = (reg & 3) + 8*(reg >> 2) + 4*hi;
        size_t base = obase + (size_t)(wave*32 + qr) * 64 + l31;
        Op[base]      = (bf16)o32[0][reg];
        Op[base + 32] = (bf16)o32[1][reg];
    }
}

// ---- merge ----
__global__ __launch_bounds__(256) void k_merge(
        const bf16* __restrict__ Op0, const bf16* __restrict__ Op1,
        const bf16* __restrict__ Op2,
        const float* __restrict__ Lp0, const float* __restrict__ Lp1,
        const float* __restrict__ Lp2,
        bf16* __restrict__ Oa) {
    int g = blockIdx.x * 256 + threadIdx.x;      // 524288 total
    int dseg = g & 7;
    int s = (g >> 3) & 2047;
    int bh = g >> 14;
    int qc = s >> 7;
    int sl = s & 127;

    size_t r0 = ((size_t)bh * 2048 + s) * 64 + dseg*8;
    bf16x8 p0 = ld_b8(Op0 + r0);
    float l = Lp0[bh*2048 + s];
    float acc[8];
#pragma unroll
    for (int i = 0; i < 8; i++) acc[i] = (float)p0[i];

    if (qc >= 5) {
        size_t r1 = ((size_t)bh * 1408 + (qc-5)*128 + sl) * 64 + dseg*8;
        bf16x8 p1 = ld_b8(Op1 + r1);
        l += Lp1[bh*1408 + (qc-5)*128 + sl];
#pragma unroll
        for (int i = 0; i < 8; i++) acc[i] += (float)p1[i];
        if (qc >= 11) {
            size_t r2 = ((size_t)bh * 640 + (qc-11)*128 + sl) * 64 + dseg*8;
            bf16x8 p2 = ld_b8(Op2 + r2);
            l += Lp2[bh*640 + (qc-11)*128 + sl];
#pragma unroll
            for (int i = 0; i < 8; i++) acc[i] += (float)p2[i];
        }
    }

    float inv = 1.0f / l;
    bf16x8 r;
#pragma unroll
    for (int i = 0; i < 8; i++) r[i] = (bf16)(acc[i] * inv);
    int b = bh >> 4, h = bh & 15;
    *(uint4*)&Oa[(((size_t)b * SEQ + s) * NH + h) * DHEAD + dseg*8] =
        __builtin_bit_cast(uint4, r);
}

// ---- fallback single-pass attention (pair structure) for small ws ----
__global__ __launch_bounds__(256, 3) void k_attn(
        const bf16* __restrict__ Q, const bf16* __restrict__ K,
        const bf16* __restrict__ Vt, bf16* __restrict__ O) {
    int bh = blockIdx.y;
    int qc = (bh >= 16) ? (15 - (int)blockIdx.x) : (int)blockIdx.x;
    int q0 = qc * QBLK;
    int tid = threadIdx.x, wave = tid >> 6, lane = tid & 63;
    int l31 = lane & 31, hi = lane >> 5;

    __shared__ __align__(16) bf16 KsL[128*64];
    __shared__ __align__(16) bf16 VsL[64*128];

    const bf16* Kg = K  + (size_t)bh * SEQ * DHEAD;
    const bf16* Vg = Vt + (size_t)bh * DHEAD * SEQ;

    int qb = q0 + wave * 32;
    int qrow = qb + l31;

    const bf16* qrow_p = Q + ((size_t)bh * SEQ + qrow) * DHEAD;
    bf16x8 qa2[4];
#pragma unroll
    for (int c = 0; c < 4; c++) qa2[c] = ld_b8(qrow_p + c*16 + hi*8);

    bf16x8 ones;
#pragma unroll
    for (int c = 0; c < 8; c++) ones[c] = (bf16)1.0f;

    const f32x16 z16 = {0,0,0,0,0,0,0,0,0,0,0,0,0,0,0,0};
    f32x16 o32[2], acc_l;
    o32[0] = z16; o32[1] = z16; acc_l = z16;

    int nt = 2*qc + 2;
    int qmax_wave = qb + 31;

#define A_STAGE(kv0s)                                                     \
    {                                                                     \
        _Pragma("unroll")                                                 \
        for (int i = 0; i < 4; i++) {                                     \
            int c2 = tid + i*256;                                         \
            int krow = c2 >> 3;                                           \
            int kch = ((c2 & 7) ^ (krow & 7)) * 8;                        \
            int kgr = (kv0s) + krow; if (kgr > SEQ-1) kgr = SEQ-1;        \
            gload_lds16(Kg + (size_t)kgr * DHEAD + kch, KsL + c2*8);      \
            int vrow = c2 >> 4;                                           \
            int vch = ((c2 & 15) ^ (vrow & 7)) * 8;                       \
            int vgc = (kv0s) + vch; if (vgc > SEQ-8) vgc = SEQ-8;         \
            gload_lds16(Vg + (size_t)vrow * SEQ + vgc, VsL + c2*8);       \
        }                                                                 \
    }

    for (int t = 0; t < nt; t += 2) {
        A_STAGE(t * KVB);
        __syncthreads();
        int kv00 = t * KVB;
        bool a1 = (t + 1 < nt) && (kv00 + KVB <= qmax_wave);
        if (kv00 <= qmax_wave) {
            f32x16 sa[2];
            sa[0] = z16; sa[1] = z16;
            if (a1) {
                f32x16 sb[2];
                sb[0] = z16; sb[1] = z16;
                a_qk(KsL, qa2, sa, 0, l31, hi);
                a_qk(KsL, qa2, sb, 1, l31, hi);
                a_rest(VsL, sa, ones, o32, acc_l, 0, kv00,     qb, qrow, l31, hi, lane);
                a_rest(VsL, sb, ones, o32, acc_l, 1, kv00+KVB, qb, qrow, l31, hi, lane);
            } else {
                a_qk(KsL, qa2, sa, 0, l31, hi);
                a_rest(VsL, sa, ones, o32, acc_l, 0, kv00, qb, qrow, l31, hi, lane);
            }
        }
        __syncthreads();
    }
#undef A_STAGE

    int b = bh >> 4, h = bh & 15;
#pragma unroll
    for (int reg = 0; reg < 16; reg++) {
        int qr = (reg & 3) + 8*(reg >> 2) + 4*hi;
        int srow2 = q0 + wave*32 + qr;
        float linv = 1.0f / acc_l[reg];
        size_t base = (((size_t)b * SEQ + srow2) * NH + h) * DHEAD + l31;
        O[base]      = (bf16)(o32[0][reg] * linv);
        O[base + 32] = (bf16)(o32[1][reg] * linv);
    }
}

// ---------------- launch ----------------

extern "C" void kernel_launch(void* const* d_in, const int* in_sizes, int n_in,
                              void* d_out, int out_size, void* d_ws, size_t ws_size,
                              hipStream_t stream) {
    const float* x     = (const float*)d_in[0];
    const float* w_qkv = (const float*)d_in[1];
    const float* b_qkv = (const float*)d_in[2];
    const float* w_out = (const float*)d_in[3];
    const float* b_out = (const float*)d_in[4];
    float* out = (float*)d_out;

    char* ws = (char*)d_ws;
    bf16* xb   = (bf16*)(ws);                      // 8.39MB; later attn output
    bf16* wqkT = (bf16*)(ws + 8388608);            // 6.29MB (dead after GEMM1 -> Lp)
    bf16* woT  = (bf16*)(ws + 14680064);           // 2.10MB
    bf16* qb   = (bf16*)(ws + 16777216);           // 8.39MB
    bf16* kb   = (bf16*)(ws + 25165824);           // 8.39MB
    bf16* vb   = (bf16*)(ws + 33554432);           // 8.39MB (V^T layout)
    bf16* Op0  = (bf16*)(ws + 41943040);           // 8.39MB (seg0, all qc)
    bf16* Op1  = (bf16*)(ws + 50331648);           // 5.77MB (seg1, qc>=5)
    bf16* Op2  = (bf16*)(ws + 56098816);           // 2.62MB (seg2, qc>=11)
    float* Lp0 = (float*)(ws + 8388608);           // in dead wqkT region
    float* Lp1 = (float*)(ws + 8388608 + 262144);
    float* Lp2 = (float*)(ws + 8388608 + 524288);
    const size_t WS_NEED = 58720256;
    bf16* attn = xb;                               // reuse x_bf16 region

    k_cvt<<<(MROWS*DMODEL/4 + 255)/256, 256, 0, stream>>>(x, xb, MROWS*DMODEL/4);
    dim3 tb(32, 8);
    k_tcvt_qkv<<<dim3(NQKV/32, DMODEL/32), tb, 0, stream>>>(w_qkv, wqkT);
    k_tcvt<<<dim3(DMODEL/32, DMODEL/32), tb, 0, stream>>>(w_out, woT, DMODEL, DMODEL);

    k_gemm_qkv<<<dim3(12, 16), 512, 0, stream>>>(xb, wqkT, b_qkv, qb, kb, vb);

    if (ws_size >= WS_NEED) {
        k_attn_split<<<dim3(256, 4), 256, 0, stream>>>(qb, kb, vb,
                                                       Op0, Op1, Op2, Lp0, Lp1, Lp2);
        k_merge<<<(NBS*NH*SEQ*DHEAD/8)/256, 256, 0, stream>>>(Op0, Op1, Op2,
                                                              Lp0, Lp1, Lp2, attn);
    } else {
        k_attn<<<dim3(SEQ/QBLK, NBS*NH), 256, 0, stream>>>(qb, kb, vb, attn);
    }

    k_gemm_out<<<dim3(DMODEL/128, MROWS/64), 256, 0, stream>>>(attn, woT, b_out, out);
}

// Round 14
// 124.897 us; speedup vs baseline: 1.0637x; 1.0637x over previous
//
#include <hip/hip_runtime.h>
#include <hip/hip_bf16.h>
#include <stdint.h>

#define NBS 2
#define SEQ 2048
#define DMODEL 1024
#define NH 16
#define DHEAD 64
#define MROWS (NBS*SEQ)     // 4096
#define NQKV (NH*3*DHEAD)   // 3072

typedef __bf16 bf16;
typedef __bf16 bf16x8 __attribute__((ext_vector_type(8)));
typedef float f32x4 __attribute__((ext_vector_type(4)));
typedef float f32x16 __attribute__((ext_vector_type(16)));
typedef unsigned int u32x2 __attribute__((ext_vector_type(2)));

#define LOG2E 1.44269504088896f
#define QSCALE (0.125f * LOG2E)

static __device__ __forceinline__ void gload_lds16(const bf16* g, bf16* l) {
    __builtin_amdgcn_global_load_lds(
        (const __attribute__((address_space(1))) uint32_t*)g,
        (__attribute__((address_space(3))) uint32_t*)l, 16, 0, 0);
}

static __device__ __forceinline__ bf16x8 ld_b8(const bf16* p) {
    return __builtin_bit_cast(bf16x8, *(const uint4*)p);
}

static __device__ __forceinline__ uint32_t pk_bf16(float lo, float hi) {
    unsigned short l = __builtin_bit_cast(unsigned short, (bf16)lo);
    unsigned short h = __builtin_bit_cast(unsigned short, (bf16)hi);
    return ((uint32_t)h << 16) | (uint32_t)l;
}

static __device__ __forceinline__ u32x2 lane_swap32(uint32_t a, uint32_t b, int lane) {
#if __has_builtin(__builtin_amdgcn_permlane32_swap)
    return __builtin_amdgcn_permlane32_swap(a, b, false, false);
#else
    uint32_t sa = __shfl_xor(a, 32), sb = __shfl_xor(b, 32);
    u32x2 r;
    r.x = (lane >= 32) ? sb : a;
    r.y = (lane >= 32) ? b : sa;
    return r;
#endif
}

// ---------------- convert kernels ----------------

__global__ void k_cvt(const float* __restrict__ in, bf16* __restrict__ out, int n4) {
    int i = blockIdx.x * blockDim.x + threadIdx.x;
    if (i < n4) {
        float4 v = ((const float4*)in)[i];
        ushort4 o;
        o.x = __builtin_bit_cast(unsigned short, (bf16)v.x);
        o.y = __builtin_bit_cast(unsigned short, (bf16)v.y);
        o.z = __builtin_bit_cast(unsigned short, (bf16)v.z);
        o.w = __builtin_bit_cast(unsigned short, (bf16)v.w);
        ((ushort4*)out)[i] = o;
    }
}

// in: [R][C] f32 row-major -> out: [C][R] bf16 (B^T for GEMM)
__global__ void k_tcvt(const float* __restrict__ in, bf16* __restrict__ out, int R, int C) {
    __shared__ float t[32][33];
    int tx = threadIdx.x, ty = threadIdx.y;   // 32 x 8
    int r0 = blockIdx.y * 32, c0 = blockIdx.x * 32;
#pragma unroll
    for (int i = 0; i < 4; i++)
        t[ty + i*8][tx] = in[(size_t)(r0 + ty + i*8) * C + (c0 + tx)];
    __syncthreads();
#pragma unroll
    for (int i = 0; i < 4; i++)
        out[(size_t)(c0 + ty + i*8) * R + (r0 + tx)] = (bf16)t[tx][ty + i*8];
}

// w_qkv variant with column permute: col(h*192+kind*64+d) -> kind*1024+h*64+d.
__global__ void k_tcvt_qkv(const float* __restrict__ in, bf16* __restrict__ out) {
    __shared__ float t[32][33];
    int tx = threadIdx.x, ty = threadIdx.y;   // 32 x 8
    int r0 = blockIdx.y * 32, c0 = blockIdx.x * 32;
#pragma unroll
    for (int i = 0; i < 4; i++)
        t[ty + i*8][tx] = in[(size_t)(r0 + ty + i*8) * NQKV + (c0 + tx)];
    __syncthreads();
#pragma unroll
    for (int i = 0; i < 4; i++) {
        int c = c0 + ty + i*8;
        int h = c / 192, f = c % 192;
        int cperm = ((f >> 6) << 10) + (h << 6) + (f & 63);
        out[(size_t)cperm * DMODEL + (r0 + tx)] = (bf16)t[tx][ty + i*8];
    }
}

// ---------------- GEMM1: 256x256 tile, BK=64, 512 thr, counted-vmcnt (R12) ----
#define G1_NT 16   // 1024/64 K-tiles

__global__ __launch_bounds__(512, 2) void k_gemm_qkv(
        const bf16* __restrict__ A, const bf16* __restrict__ Bt,
        const float* __restrict__ bias,
        bf16* __restrict__ Q, bf16* __restrict__ Kp, bf16* __restrict__ Vt) {
    __shared__ __align__(16) bf16 As[2][256*64];
    __shared__ __align__(16) bf16 Bs[2][256*64];
    int tid = threadIdx.x;
    int wid = tid >> 6, lane = tid & 63;
    int wr = wid >> 2, wc = wid & 3;
    int g = lane >> 4, r = lane & 15;

    int lid = blockIdx.y * 12 + blockIdx.x;
    int swz = (lid & 7) * 24 + (lid >> 3);
    int tile_n = (swz % 12) * 256, tile_m = (swz / 12) * 256;

    f32x4 acc[8][4];
#pragma unroll
    for (int m = 0; m < 8; m++)
#pragma unroll
        for (int n = 0; n < 4; n++)
            acc[m][n] = (f32x4){0.f, 0.f, 0.f, 0.f};

    int srow[4], schk[4];
#pragma unroll
    for (int j2 = 0; j2 < 4; j2++) {
        int idx = tid + j2 * 512;
        srow[j2] = idx >> 3;
        schk[j2] = ((idx & 7) ^ (srow[j2] & 7)) * 8;
    }

#define G1_STAGE(buf, k0)                                                        \
    {                                                                            \
        _Pragma("unroll")                                                        \
        for (int j2 = 0; j2 < 4; j2++) {                                         \
            gload_lds16(A  + (size_t)(tile_m + srow[j2]) * DMODEL + (k0) + schk[j2], \
                        As[buf] + (tid + j2*512) * 8);                           \
            gload_lds16(Bt + (size_t)(tile_n + srow[j2]) * DMODEL + (k0) + schk[j2], \
                        Bs[buf] + (tid + j2*512) * 8);                           \
        }                                                                        \
    }

    G1_STAGE(0, 0);

    int r7 = r & 7;
    for (int t = 0; t < G1_NT; t++) {
        int cur = t & 1;
        if (t + 1 < G1_NT) {
            G1_STAGE(cur ^ 1, (t + 1) * 64);
            asm volatile("s_waitcnt vmcnt(8)" ::: "memory");
        } else {
            asm volatile("s_waitcnt vmcnt(0)" ::: "memory");
        }
        __builtin_amdgcn_s_barrier();
        __builtin_amdgcn_sched_barrier(0);

        const bf16* pa = As[cur];
        const bf16* pb = Bs[cur];
#pragma unroll
        for (int kk = 0; kk < 2; kk++) {
            int rchk = ((kk*4 + g) ^ r7) * 8;
            bf16x8 bfr[4];
#pragma unroll
            for (int n = 0; n < 4; n++)
                bfr[n] = ld_b8(pb + (wc*64 + n*16 + r) * 64 + rchk);
#pragma unroll
            for (int m = 0; m < 8; m++) {
                bf16x8 af = ld_b8(pa + (wr*128 + m*16 + r) * 64 + rchk);
#pragma unroll
                for (int n = 0; n < 4; n++)
                    acc[m][n] = __builtin_amdgcn_mfma_f32_16x16x32_bf16(af, bfr[n], acc[m][n], 0, 0, 0);
            }
        }
        asm volatile("s_waitcnt lgkmcnt(0)" ::: "memory");
        __builtin_amdgcn_s_barrier();
    }

#pragma unroll
    for (int m = 0; m < 8; m++) {
#pragma unroll
        for (int n = 0; n < 4; n++) {
            int col = tile_n + wc*64 + n*16 + r;
            int kind = col >> 10;
            int h = (col >> 6) & 15;
            int d = col & 63;
            float bv = bias[h*192 + (kind << 6) + d];
            if (kind == 2) {
                int row0 = tile_m + wr*128 + m*16 + g*4;
                int b = row0 >> 11, s0 = row0 & 2047;
                ushort4 vv;
                vv.x = __builtin_bit_cast(unsigned short, (bf16)(acc[m][n][0] + bv));
                vv.y = __builtin_bit_cast(unsigned short, (bf16)(acc[m][n][1] + bv));
                vv.z = __builtin_bit_cast(unsigned short, (bf16)(acc[m][n][2] + bv));
                vv.w = __builtin_bit_cast(unsigned short, (bf16)(acc[m][n][3] + bv));
                *(ushort4*)&Vt[(((size_t)(b*NH + h)) * DHEAD + d) * SEQ + s0] = vv;
            } else {
#pragma unroll
                for (int j = 0; j < 4; j++) {
                    int row = tile_m + wr*128 + m*16 + g*4 + j;
                    int b = row >> 11, s = row & 2047;
                    float v = acc[m][n][j] + bv;
                    size_t addr = (((size_t)(b*NH + h)) * SEQ + s) * DHEAD + d;
                    if (kind == 0) Q[addr]  = (bf16)(v * QSCALE);
                    else           Kp[addr] = (bf16)v;
                }
            }
        }
    }
#undef G1_STAGE
}

// ---- gemm_out: 64x128 tile, 4 waves, 2-barrier, grid 512 ----
__global__ __launch_bounds__(256) void k_gemm_out(
        const bf16* __restrict__ A, const bf16* __restrict__ Bt,
        const float* __restrict__ bias, float* __restrict__ out) {
    __shared__ __align__(16) bf16 As[64*32];
    __shared__ __align__(16) bf16 Bs[128*32];
    int tid = threadIdx.x;
    int wave = tid >> 6, lane = tid & 63;
    int g = lane >> 4, r = lane & 15;
    int srow = lane >> 2, schunk = (lane & 3) * 8;
    int tile_m = blockIdx.y * 64, tile_n = blockIdx.x * 128;

    f32x4 acc[4][2];
#pragma unroll
    for (int m = 0; m < 4; m++)
#pragma unroll
        for (int n = 0; n < 2; n++)
            acc[m][n] = (f32x4){0.f, 0.f, 0.f, 0.f};

    for (int k0 = 0; k0 < DMODEL; k0 += 32) {
        gload_lds16(A  + (size_t)(tile_m + wave*16 + srow) * DMODEL + k0 + schunk, As + wave*512);
        gload_lds16(Bt + (size_t)(tile_n + wave*16 + srow) * DMODEL + k0 + schunk, Bs + wave*512);
        gload_lds16(Bt + (size_t)(tile_n + 64 + wave*16 + srow) * DMODEL + k0 + schunk, Bs + 2048 + wave*512);
        __syncthreads();
        bf16x8 af[4], bfr[2];
#pragma unroll
        for (int m = 0; m < 4; m++) af[m]  = *(const bf16x8*)(As + (m*16 + r)*32 + g*8);
#pragma unroll
        for (int n = 0; n < 2; n++) bfr[n] = *(const bf16x8*)(Bs + (wave*32 + n*16 + r)*32 + g*8);
#pragma unroll
        for (int m = 0; m < 4; m++)
#pragma unroll
            for (int n = 0; n < 2; n++)
                acc[m][n] = __builtin_amdgcn_mfma_f32_16x16x32_bf16(af[m], bfr[n], acc[m][n], 0, 0, 0);
        __syncthreads();
    }

#pragma unroll
    for (int m = 0; m < 4; m++) {
#pragma unroll
        for (int n = 0; n < 2; n++) {
            int col = tile_n + wave*32 + n*16 + r;
            float bv = bias[col];
#pragma unroll
            for (int j = 0; j < 4; j++) {
                int row = tile_m + m*16 + g*4 + j;
                out[(size_t)row * DMODEL + col] = acc[m][n][j] + bv;
            }
        }
    }
}

// ---------------- flash attention v7: gload_lds dbuf + counted vmcnt ----------
// K tile [64][64], V^T tile [64][64], both XOR chunk^(row&7), double-buffered.
// Per tile: STAGE(buf^1, t+1) -> vmcnt(4) -> s_barrier -> compute(buf)
// -> lgkmcnt(0) -> s_barrier. 4 gload_lds/thread/tile, zero ds_writes.
#define QBLK 128
#define KVB 64

static __device__ __forceinline__ void a_qk(
        const bf16* Ks, const bf16x8 qa2[4], f32x16 st[2], int l31, int hi) {
    int sw = (l31 & 7) << 3;
    __builtin_amdgcn_s_setprio(1);
#pragma unroll
    for (int rb = 0; rb < 2; rb++)
#pragma unroll
        for (int c = 0; c < 4; c++) {
            bf16x8 kf = ld_b8(Ks + (rb*32 + l31)*64 + ((c*16 + hi*8) ^ sw));
            st[rb] = __builtin_amdgcn_mfma_f32_32x32x16_bf16(kf, qa2[c], st[rb], 0, 0, 0);
        }
    __builtin_amdgcn_s_setprio(0);
}

static __device__ __forceinline__ void a_rest(
        const bf16* VsT, f32x16 st[2], const bf16x8& ones,
        f32x16 o32[2], f32x16& acc_l,
        int kvb, int qb, int qrow, int l31, int hi, int lane) {
    bool needm = (kvb + KVB - 1) > qb;
#pragma unroll
    for (int rb = 0; rb < 2; rb++)
#pragma unroll
        for (int reg = 0; reg < 16; reg++) {
            float e = __builtin_amdgcn_exp2f(st[rb][reg]);
            if (needm) {
                int kv = kvb + rb*32 + (reg & 3) + 8*(reg >> 2) + 4*hi;
                if (kv > qrow) e = 0.f;
            }
            st[rb][reg] = e;
        }

    bf16x8 pa[4];
#pragma unroll
    for (int c = 0; c < 4; c++) {
        const f32x16& pp = st[c >> 1];
        const int base = (c & 1) * 8;
        uint32_t a0 = pk_bf16(pp[base+0], pp[base+1]);
        uint32_t a1 = pk_bf16(pp[base+2], pp[base+3]);
        uint32_t b0 = pk_bf16(pp[base+4], pp[base+5]);
        uint32_t b1 = pk_bf16(pp[base+6], pp[base+7]);
        u32x2 s0 = lane_swap32(a0, b0, lane);
        u32x2 s1 = lane_swap32(a1, b1, lane);
        uint4 fr = {s0.x, s1.x, s0.y, s1.y};
        pa[c] = __builtin_bit_cast(bf16x8, fr);
    }

    int sw = (l31 & 7) << 3;
    __builtin_amdgcn_s_setprio(1);
#pragma unroll
    for (int dblk = 0; dblk < 2; dblk++)
#pragma unroll
        for (int c = 0; c < 4; c++) {
            bf16x8 vf = ld_b8(VsT + (dblk*32 + l31)*64 + ((c*16 + hi*8) ^ sw));
            o32[dblk] = __builtin_amdgcn_mfma_f32_32x32x16_bf16(pa[c], vf, o32[dblk], 0, 0, 0);
        }
#pragma unroll
    for (int c = 0; c < 4; c++)
        acc_l = __builtin_amdgcn_mfma_f32_32x32x16_bf16(pa[c], ones, acc_l, 0, 0, 0);
    __builtin_amdgcn_s_setprio(0);
}

// ---- equal-length job tables (R8) ----
__device__ const int8_t JQC[32]  = {10,10, 4, 0, 15,15, 3, 1,  9, 9, 7, 2, 13,14, 7, 5,
                                    14,14,11, 5, 15, 8,11, 6,  8,12,12, 6, 13,13,11,12};
__device__ const int8_t JT0[32]  = { 0,11, 0, 0,  0,11, 0, 0,  0,10, 0, 0,  0, 0, 8, 0,
                                    10,20, 0, 6, 22, 0, 8, 0,  9, 0, 9, 7, 10,19,16,18};
__device__ const int8_t JT1[32]  = {11,22,10, 2, 11,22, 8, 4, 10,20, 8, 6, 10,10,16, 6,
                                    20,30, 8,12, 32, 9,16, 7, 18, 9,18,14, 19,28,24,26};
__device__ const int8_t JSEG[32] = { 0, 1, 0, 0,  0, 1, 0, 0,  0, 1, 0, 0,  0, 0, 1, 0,
                                     1, 2, 0, 1,  2, 0, 1, 0,  1, 0, 1, 1,  1, 2, 2, 2};

__global__ __launch_bounds__(256) void k_attn_split(
        const bf16* __restrict__ Q, const bf16* __restrict__ K,
        const bf16* __restrict__ Vt,
        bf16* __restrict__ Op0, bf16* __restrict__ Op1, bf16* __restrict__ Op2,
        float* __restrict__ Lp0, float* __restrict__ Lp1, float* __restrict__ Lp2) {
    int scu = blockIdx.x;
    int bh = scu >> 3, slot = scu & 7;
    int j = slot * 4 + blockIdx.y;
    int qc  = JQC[j];
    int t0  = JT0[j];
    int t1  = JT1[j];
    int seg = JSEG[j];
    int q0 = qc * QBLK;
    int tid = threadIdx.x, wave = tid >> 6, lane = tid & 63;
    int l31 = lane & 31, hi = lane >> 5;

    __shared__ __align__(16) bf16 Ks[2][KVB*64];   // 2 x 8KB
    __shared__ __align__(16) bf16 VsT[2][KVB*64];  // 2 x 8KB

    const bf16* Kg = K  + (size_t)bh * SEQ * DHEAD;
    const bf16* Vg = Vt + (size_t)bh * DHEAD * SEQ;

    int qb = q0 + wave * 32;
    int qrow = qb + l31;

    const bf16* qrow_p = Q + ((size_t)bh * SEQ + qrow) * DHEAD;
    bf16x8 qa2[4];
#pragma unroll
    for (int c = 0; c < 4; c++) qa2[c] = ld_b8(qrow_p + c*16 + hi*8);

    bf16x8 ones;
#pragma unroll
    for (int c = 0; c < 8; c++) ones[c] = (bf16)1.0f;

    const f32x16 z16 = {0,0,0,0,0,0,0,0,0,0,0,0,0,0,0,0};
    f32x16 o32[2], acc_l;
    o32[0] = z16; o32[1] = z16; acc_l = z16;

    int qmax_wave = qb + 31;

    // staging: 2 chunks K + 2 chunks V per thread; linear dest, XOR'd source
    int c2a = tid, c2b = tid + 256;
    int rowA = c2a >> 3, chA = ((c2a & 7) ^ (rowA & 7)) * 8;
    int rowB = c2b >> 3, chB = ((c2b & 7) ^ (rowB & 7)) * 8;

#define A_STAGE(buf, kv0s)                                                    \
    {                                                                         \
        gload_lds16(Kg + (size_t)((kv0s) + rowA) * DHEAD + chA, Ks[buf] + c2a*8);  \
        gload_lds16(Kg + (size_t)((kv0s) + rowB) * DHEAD + chB, Ks[buf] + c2b*8);  \
        gload_lds16(Vg + (size_t)rowA * SEQ + (kv0s) + chA, VsT[buf] + c2a*8);     \
        gload_lds16(Vg + (size_t)rowB * SEQ + (kv0s) + chB, VsT[buf] + c2b*8);     \
    }

    A_STAGE(0, t0 * KVB);

    for (int t = t0; t < t1; t++) {
        int cur = (t - t0) & 1;
        if (t + 1 < t1) {
            A_STAGE(cur ^ 1, (t + 1) * KVB);
            asm volatile("s_waitcnt vmcnt(4)" ::: "memory");
        } else {
            asm volatile("s_waitcnt vmcnt(0)" ::: "memory");
        }
        __builtin_amdgcn_s_barrier();
        __builtin_amdgcn_sched_barrier(0);

        int kv0 = t * KVB;
        if (kv0 <= qmax_wave) {
            f32x16 st[2];
            st[0] = z16; st[1] = z16;
            a_qk(Ks[cur], qa2, st, l31, hi);
            a_rest(VsT[cur], st, ones, o32, acc_l, kv0, qb, qrow, l31, hi, lane);
        }
        asm volatile("s_waitcnt lgkmcnt(0)" ::: "memory");
        __builtin_amdgcn_s_barrier();
    }
#undef A_STAGE

    bf16* Op; float* Lp; size_t obase; int lbase;
    if (seg == 0)      { Op = Op0; Lp = Lp0; obase = ((size_t)bh*2048 + q0) * 64;          lbase = bh*2048 + q0; }
    else if (seg == 1) { Op = Op1; Lp = Lp1; obase = ((size_t)bh*1408 + (qc-5)*128) * 64;  lbase = bh*1408 + (qc-5)*128; }
    else               { Op = Op2; Lp = Lp2; obase = ((size_t)bh*640  + (qc-11)*128) * 64; lbase = bh*640  + (qc-11)*128; }

    if (l31 == 0) {
#pragma unroll
        for (int reg = 0; reg < 16; reg++) {
            int qr = (reg & 3) + 8*(reg >> 2) + 4*hi;
            Lp[lbase + wave*32 + qr] = acc_l[reg];
        }
    }

#pragma unroll
    for (int reg = 0; reg < 16; reg++) {
        int qr = (reg & 3) + 8*(reg >> 2) + 4*hi;
        size_t base = obase + (size_t)(wave*32 + qr) * 64 + l31;
        Op[base]      = (bf16)o32[0][reg];
        Op[base + 32] = (bf16)o32[1][reg];
    }
}

// ---- merge ----
__global__ __launch_bounds__(256) void k_merge(
        const bf16* __restrict__ Op0, const bf16* __restrict__ Op1,
        const bf16* __restrict__ Op2,
        const float* __restrict__ Lp0, const float* __restrict__ Lp1,
        const float* __restrict__ Lp2,
        bf16* __restrict__ Oa) {
    int g = blockIdx.x * 256 + threadIdx.x;      // 524288 total
    int dseg = g & 7;
    int s = (g >> 3) & 2047;
    int bh = g >> 14;
    int qc = s >> 7;
    int sl = s & 127;

    size_t r0 = ((size_t)bh * 2048 + s) * 64 + dseg*8;
    bf16x8 p0 = ld_b8(Op0 + r0);
    float l = Lp0[bh*2048 + s];
    float acc[8];
#pragma unroll
    for (int i = 0; i < 8; i++) acc[i] = (float)p0[i];

    if (qc >= 5) {
        size_t r1 = ((size_t)bh * 1408 + (qc-5)*128 + sl) * 64 + dseg*8;
        bf16x8 p1 = ld_b8(Op1 + r1);
        l += Lp1[bh*1408 + (qc-5)*128 + sl];
#pragma unroll
        for (int i = 0; i < 8; i++) acc[i] += (float)p1[i];
        if (qc >= 11) {
            size_t r2 = ((size_t)bh * 640 + (qc-11)*128 + sl) * 64 + dseg*8;
            bf16x8 p2 = ld_b8(Op2 + r2);
            l += Lp2[bh*640 + (qc-11)*128 + sl];
#pragma unroll
            for (int i = 0; i < 8; i++) acc[i] += (float)p2[i];
        }
    }

    float inv = 1.0f / l;
    bf16x8 r;
#pragma unroll
    for (int i = 0; i < 8; i++) r[i] = (bf16)(acc[i] * inv);
    int b = bh >> 4, h = bh & 15;
    *(uint4*)&Oa[(((size_t)b * SEQ + s) * NH + h) * DHEAD + dseg*8] =
        __builtin_bit_cast(uint4, r);
}

// ---- fallback single-pass attention (same v7 structure) for small ws ----
__global__ __launch_bounds__(256) void k_attn(
        const bf16* __restrict__ Q, const bf16* __restrict__ K,
        const bf16* __restrict__ Vt, bf16* __restrict__ O) {
    int bh = blockIdx.y;
    int qc = (bh >= 16) ? (15 - (int)blockIdx.x) : (int)blockIdx.x;
    int q0 = qc * QBLK;
    int tid = threadIdx.x, wave = tid >> 6, lane = tid & 63;
    int l31 = lane & 31, hi = lane >> 5;

    __shared__ __align__(16) bf16 Ks[2][KVB*64];
    __shared__ __align__(16) bf16 VsT[2][KVB*64];

    const bf16* Kg = K  + (size_t)bh * SEQ * DHEAD;
    const bf16* Vg = Vt + (size_t)bh * DHEAD * SEQ;

    int qb = q0 + wave * 32;
    int qrow = qb + l31;

    const bf16* qrow_p = Q + ((size_t)bh * SEQ + qrow) * DHEAD;
    bf16x8 qa2[4];
#pragma unroll
    for (int c = 0; c < 4; c++) qa2[c] = ld_b8(qrow_p + c*16 + hi*8);

    bf16x8 ones;
#pragma unroll
    for (int c = 0; c < 8; c++) ones[c] = (bf16)1.0f;

    const f32x16 z16 = {0,0,0,0,0,0,0,0,0,0,0,0,0,0,0,0};
    f32x16 o32[2], acc_l;
    o32[0] = z16; o32[1] = z16; acc_l = z16;

    int nt = 2*qc + 2;
    int qmax_wave = qb + 31;

    int c2a = tid, c2b = tid + 256;
    int rowA = c2a >> 3, chA = ((c2a & 7) ^ (rowA & 7)) * 8;
    int rowB = c2b >> 3, chB = ((c2b & 7) ^ (rowB & 7)) * 8;

#define A_STAGE(buf, kv0s)                                                    \
    {                                                                         \
        gload_lds16(Kg + (size_t)((kv0s) + rowA) * DHEAD + chA, Ks[buf] + c2a*8);  \
        gload_lds16(Kg + (size_t)((kv0s) + rowB) * DHEAD + chB, Ks[buf] + c2b*8);  \
        gload_lds16(Vg + (size_t)rowA * SEQ + (kv0s) + chA, VsT[buf] + c2a*8);     \
        gload_lds16(Vg + (size_t)rowB * SEQ + (kv0s) + chB, VsT[buf] + c2b*8);     \
    }

    A_STAGE(0, 0);

    for (int t = 0; t < nt; t++) {
        int cur = t & 1;
        if (t + 1 < nt) {
            A_STAGE(cur ^ 1, (t + 1) * KVB);
            asm volatile("s_waitcnt vmcnt(4)" ::: "memory");
        } else {
            asm volatile("s_waitcnt vmcnt(0)" ::: "memory");
        }
        __builtin_amdgcn_s_barrier();
        __builtin_amdgcn_sched_barrier(0);

        int kv0 = t * KVB;
        if (kv0 <= qmax_wave) {
            f32x16 st[2];
            st[0] = z16; st[1] = z16;
            a_qk(Ks[cur], qa2, st, l31, hi);
            a_rest(VsT[cur], st, ones, o32, acc_l, kv0, qb, qrow, l31, hi, lane);
        }
        asm volatile("s_waitcnt lgkmcnt(0)" ::: "memory");
        __builtin_amdgcn_s_barrier();
    }
#undef A_STAGE

    int b = bh >> 4, h = bh & 15;
#pragma unroll
    for (int reg = 0; reg < 16; reg++) {
        int qr = (reg & 3) + 8*(reg >> 2) + 4*hi;
        int srow2 = q0 + wave*32 + qr;
        float linv = 1.0f / acc_l[reg];
        size_t base = (((size_t)b * SEQ + srow2) * NH + h) * DHEAD + l31;
        O[base]      = (bf16)(o32[0][reg] * linv);
        O[base + 32] = (bf16)(o32[1][reg] * linv);
    }
}

// ---------------- launch ----------------

extern "C" void kernel_launch(void* const* d_in, const int* in_sizes, int n_in,
                              void* d_out, int out_size, void* d_ws, size_t ws_size,
                              hipStream_t stream) {
    const float* x     = (const float*)d_in[0];
    const float* w_qkv = (const float*)d_in[1];
    const float* b_qkv = (const float*)d_in[2];
    const float* w_out = (const float*)d_in[3];
    const float* b_out = (const float*)d_in[4];
    float* out = (float*)d_out;

    char* ws = (char*)d_ws;
    bf16* xb   = (bf16*)(ws);                      // 8.39MB; later attn output
    bf16* wqkT = (bf16*)(ws + 8388608);            // 6.29MB (dead after GEMM1 -> Lp)
    bf16* woT  = (bf16*)(ws + 14680064);           // 2.10MB
    bf16* qb   = (bf16*)(ws + 16777216);           // 8.39MB
    bf16* kb   = (bf16*)(ws + 25165824);           // 8.39MB
    bf16* vb   = (bf16*)(ws + 33554432);           // 8.39MB (V^T layout)
    bf16* Op0  = (bf16*)(ws + 41943040);           // 8.39MB (seg0, all qc)
    bf16* Op1  = (bf16*)(ws + 50331648);           // 5.77MB (seg1, qc>=5)
    bf16* Op2  = (bf16*)(ws + 56098816);           // 2.62MB (seg2, qc>=11)
    float* Lp0 = (float*)(ws + 8388608);           // in dead wqkT region
    float* Lp1 = (float*)(ws + 8388608 + 262144);
    float* Lp2 = (float*)(ws + 8388608 + 524288);
    const size_t WS_NEED = 58720256;
    bf16* attn = xb;                               // reuse x_bf16 region

    k_cvt<<<(MROWS*DMODEL/4 + 255)/256, 256, 0, stream>>>(x, xb, MROWS*DMODEL/4);
    dim3 tb(32, 8);
    k_tcvt_qkv<<<dim3(NQKV/32, DMODEL/32), tb, 0, stream>>>(w_qkv, wqkT);
    k_tcvt<<<dim3(DMODEL/32, DMODEL/32), tb, 0, stream>>>(w_out, woT, DMODEL, DMODEL);

    k_gemm_qkv<<<dim3(12, 16), 512, 0, stream>>>(xb, wqkT, b_qkv, qb, kb, vb);

    if (ws_size >= WS_NEED) {
        k_attn_split<<<dim3(256, 4), 256, 0, stream>>>(qb, kb, vb,
                                                       Op0, Op1, Op2, Lp0, Lp1, Lp2);
        k_merge<<<(NBS*NH*SEQ*DHEAD/8)/256, 256, 0, stream>>>(Op0, Op1, Op2,
                                                              Lp0, Lp1, Lp2, attn);
    } else {
        k_attn<<<dim3(SEQ/QBLK, NBS*NH), 256, 0, stream>>>(qb, kb, vb, attn);
    }

    k_gemm_out<<<dim3(DMODEL/128, MROWS/64), 256, 0, stream>>>(attn, woT, b_out, out);
}

// Round 15
// 123.069 us; speedup vs baseline: 1.0795x; 1.0149x over previous
//
#include <hip/hip_runtime.h>
#include <hip/hip_bf16.h>
#include <stdint.h>

#define NBS 2
#define SEQ 2048
#define DMODEL 1024
#define NH 16
#define DHEAD 64
#define MROWS (NBS*SEQ)     // 4096
#define NQKV (NH*3*DHEAD)   // 3072

typedef __bf16 bf16;
typedef __bf16 bf16x8 __attribute__((ext_vector_type(8)));
typedef float f32x4 __attribute__((ext_vector_type(4)));
typedef float f32x16 __attribute__((ext_vector_type(16)));
typedef unsigned int u32x2 __attribute__((ext_vector_type(2)));

#define LOG2E 1.44269504088896f
#define QSCALE (0.125f * LOG2E)

static __device__ __forceinline__ void gload_lds16(const bf16* g, bf16* l) {
    __builtin_amdgcn_global_load_lds(
        (const __attribute__((address_space(1))) uint32_t*)g,
        (__attribute__((address_space(3))) uint32_t*)l, 16, 0, 0);
}

static __device__ __forceinline__ bf16x8 ld_b8(const bf16* p) {
    return __builtin_bit_cast(bf16x8, *(const uint4*)p);
}

static __device__ __forceinline__ uint32_t pk_bf16(float lo, float hi) {
    unsigned short l = __builtin_bit_cast(unsigned short, (bf16)lo);
    unsigned short h = __builtin_bit_cast(unsigned short, (bf16)hi);
    return ((uint32_t)h << 16) | (uint32_t)l;
}

static __device__ __forceinline__ u32x2 lane_swap32(uint32_t a, uint32_t b, int lane) {
#if __has_builtin(__builtin_amdgcn_permlane32_swap)
    return __builtin_amdgcn_permlane32_swap(a, b, false, false);
#else
    uint32_t sa = __shfl_xor(a, 32), sb = __shfl_xor(b, 32);
    u32x2 r;
    r.x = (lane >= 32) ? sb : a;
    r.y = (lane >= 32) ? b : sa;
    return r;
#endif
}

// ---------------- convert kernels ----------------

__global__ void k_cvt(const float* __restrict__ in, bf16* __restrict__ out, int n4) {
    int i = blockIdx.x * blockDim.x + threadIdx.x;
    if (i < n4) {
        float4 v = ((const float4*)in)[i];
        ushort4 o;
        o.x = __builtin_bit_cast(unsigned short, (bf16)v.x);
        o.y = __builtin_bit_cast(unsigned short, (bf16)v.y);
        o.z = __builtin_bit_cast(unsigned short, (bf16)v.z);
        o.w = __builtin_bit_cast(unsigned short, (bf16)v.w);
        ((ushort4*)out)[i] = o;
    }
}

// in: [R][C] f32 row-major -> out: [C][R] bf16 (B^T for GEMM)
__global__ void k_tcvt(const float* __restrict__ in, bf16* __restrict__ out, int R, int C) {
    __shared__ float t[32][33];
    int tx = threadIdx.x, ty = threadIdx.y;   // 32 x 8
    int r0 = blockIdx.y * 32, c0 = blockIdx.x * 32;
#pragma unroll
    for (int i = 0; i < 4; i++)
        t[ty + i*8][tx] = in[(size_t)(r0 + ty + i*8) * C + (c0 + tx)];
    __syncthreads();
#pragma unroll
    for (int i = 0; i < 4; i++)
        out[(size_t)(c0 + ty + i*8) * R + (r0 + tx)] = (bf16)t[tx][ty + i*8];
}

// w_qkv variant with column permute: col(h*192+kind*64+d) -> kind*1024+h*64+d.
__global__ void k_tcvt_qkv(const float* __restrict__ in, bf16* __restrict__ out) {
    __shared__ float t[32][33];
    int tx = threadIdx.x, ty = threadIdx.y;   // 32 x 8
    int r0 = blockIdx.y * 32, c0 = blockIdx.x * 32;
#pragma unroll
    for (int i = 0; i < 4; i++)
        t[ty + i*8][tx] = in[(size_t)(r0 + ty + i*8) * NQKV + (c0 + tx)];
    __syncthreads();
#pragma unroll
    for (int i = 0; i < 4; i++) {
        int c = c0 + ty + i*8;
        int h = c / 192, f = c % 192;
        int cperm = ((f >> 6) << 10) + (h << 6) + (f & 63);
        out[(size_t)cperm * DMODEL + (r0 + tx)] = (bf16)t[tx][ty + i*8];
    }
}

// ---------------- GEMM1: 256x256 tile, BK=64, 512 thr, counted-vmcnt (R12) ----
#define G1_NT 16   // 1024/64 K-tiles

__global__ __launch_bounds__(512, 2) void k_gemm_qkv(
        const bf16* __restrict__ A, const bf16* __restrict__ Bt,
        const float* __restrict__ bias,
        bf16* __restrict__ Q, bf16* __restrict__ Kp, bf16* __restrict__ Vt) {
    __shared__ __align__(16) bf16 As[2][256*64];
    __shared__ __align__(16) bf16 Bs[2][256*64];
    int tid = threadIdx.x;
    int wid = tid >> 6, lane = tid & 63;
    int wr = wid >> 2, wc = wid & 3;
    int g = lane >> 4, r = lane & 15;

    int lid = blockIdx.y * 12 + blockIdx.x;
    int swz = (lid & 7) * 24 + (lid >> 3);
    int tile_n = (swz % 12) * 256, tile_m = (swz / 12) * 256;

    f32x4 acc[8][4];
#pragma unroll
    for (int m = 0; m < 8; m++)
#pragma unroll
        for (int n = 0; n < 4; n++)
            acc[m][n] = (f32x4){0.f, 0.f, 0.f, 0.f};

    int srow[4], schk[4];
#pragma unroll
    for (int j2 = 0; j2 < 4; j2++) {
        int idx = tid + j2 * 512;
        srow[j2] = idx >> 3;
        schk[j2] = ((idx & 7) ^ (srow[j2] & 7)) * 8;
    }

#define G1_STAGE(buf, k0)                                                        \
    {                                                                            \
        _Pragma("unroll")                                                        \
        for (int j2 = 0; j2 < 4; j2++) {                                         \
            gload_lds16(A  + (size_t)(tile_m + srow[j2]) * DMODEL + (k0) + schk[j2], \
                        As[buf] + (tid + j2*512) * 8);                           \
            gload_lds16(Bt + (size_t)(tile_n + srow[j2]) * DMODEL + (k0) + schk[j2], \
                        Bs[buf] + (tid + j2*512) * 8);                           \
        }                                                                        \
    }

    G1_STAGE(0, 0);

    int r7 = r & 7;
    for (int t = 0; t < G1_NT; t++) {
        int cur = t & 1;
        if (t + 1 < G1_NT) {
            G1_STAGE(cur ^ 1, (t + 1) * 64);
            asm volatile("s_waitcnt vmcnt(8)" ::: "memory");
        } else {
            asm volatile("s_waitcnt vmcnt(0)" ::: "memory");
        }
        __builtin_amdgcn_s_barrier();
        __builtin_amdgcn_sched_barrier(0);

        const bf16* pa = As[cur];
        const bf16* pb = Bs[cur];
#pragma unroll
        for (int kk = 0; kk < 2; kk++) {
            int rchk = ((kk*4 + g) ^ r7) * 8;
            bf16x8 bfr[4];
#pragma unroll
            for (int n = 0; n < 4; n++)
                bfr[n] = ld_b8(pb + (wc*64 + n*16 + r) * 64 + rchk);
#pragma unroll
            for (int m = 0; m < 8; m++) {
                bf16x8 af = ld_b8(pa + (wr*128 + m*16 + r) * 64 + rchk);
#pragma unroll
                for (int n = 0; n < 4; n++)
                    acc[m][n] = __builtin_amdgcn_mfma_f32_16x16x32_bf16(af, bfr[n], acc[m][n], 0, 0, 0);
            }
        }
        asm volatile("s_waitcnt lgkmcnt(0)" ::: "memory");
        __builtin_amdgcn_s_barrier();
    }

#pragma unroll
    for (int m = 0; m < 8; m++) {
#pragma unroll
        for (int n = 0; n < 4; n++) {
            int col = tile_n + wc*64 + n*16 + r;
            int kind = col >> 10;
            int h = (col >> 6) & 15;
            int d = col & 63;
            float bv = bias[h*192 + (kind << 6) + d];
            if (kind == 2) {
                int row0 = tile_m + wr*128 + m*16 + g*4;
                int b = row0 >> 11, s0 = row0 & 2047;
                ushort4 vv;
                vv.x = __builtin_bit_cast(unsigned short, (bf16)(acc[m][n][0] + bv));
                vv.y = __builtin_bit_cast(unsigned short, (bf16)(acc[m][n][1] + bv));
                vv.z = __builtin_bit_cast(unsigned short, (bf16)(acc[m][n][2] + bv));
                vv.w = __builtin_bit_cast(unsigned short, (bf16)(acc[m][n][3] + bv));
                *(ushort4*)&Vt[(((size_t)(b*NH + h)) * DHEAD + d) * SEQ + s0] = vv;
            } else {
#pragma unroll
                for (int j = 0; j < 4; j++) {
                    int row = tile_m + wr*128 + m*16 + g*4 + j;
                    int b = row >> 11, s = row & 2047;
                    float v = acc[m][n][j] + bv;
                    size_t addr = (((size_t)(b*NH + h)) * SEQ + s) * DHEAD + d;
                    if (kind == 0) Q[addr]  = (bf16)(v * QSCALE);
                    else           Kp[addr] = (bf16)v;
                }
            }
        }
    }
#undef G1_STAGE
}

// ---- gemm_out: 64x128 tile, dbuf + counted vmcnt, grid 512 = 2/CU ----
__global__ __launch_bounds__(256) void k_gemm_out(
        const bf16* __restrict__ A, const bf16* __restrict__ Bt,
        const float* __restrict__ bias, float* __restrict__ out) {
    __shared__ __align__(16) bf16 As[2][64*32];
    __shared__ __align__(16) bf16 Bs[2][128*32];
    int tid = threadIdx.x;
    int wave = tid >> 6, lane = tid & 63;
    int g = lane >> 4, r = lane & 15;
    int srow = lane >> 2, schunk = (lane & 3) * 8;
    int tile_m = blockIdx.y * 64, tile_n = blockIdx.x * 128;

    f32x4 acc[4][2];
#pragma unroll
    for (int m = 0; m < 4; m++)
#pragma unroll
        for (int n = 0; n < 2; n++)
            acc[m][n] = (f32x4){0.f, 0.f, 0.f, 0.f};

#define GO_STAGE(buf, k0)                                                                 \
    {                                                                                     \
        gload_lds16(A  + (size_t)(tile_m + wave*16 + srow) * DMODEL + (k0) + schunk,      \
                    As[buf] + wave*512);                                                  \
        gload_lds16(Bt + (size_t)(tile_n + wave*16 + srow) * DMODEL + (k0) + schunk,      \
                    Bs[buf] + wave*512);                                                  \
        gload_lds16(Bt + (size_t)(tile_n + 64 + wave*16 + srow) * DMODEL + (k0) + schunk, \
                    Bs[buf] + 2048 + wave*512);                                           \
    }

    GO_STAGE(0, 0);

    for (int t = 0; t < 32; t++) {
        int cur = t & 1;
        if (t + 1 < 32) {
            GO_STAGE(cur ^ 1, (t + 1) * 32);
            asm volatile("s_waitcnt vmcnt(3)" ::: "memory");
        } else {
            asm volatile("s_waitcnt vmcnt(0)" ::: "memory");
        }
        __builtin_amdgcn_s_barrier();
        __builtin_amdgcn_sched_barrier(0);

        bf16x8 af[4], bfr[2];
#pragma unroll
        for (int m = 0; m < 4; m++) af[m]  = *(const bf16x8*)(As[cur] + (m*16 + r)*32 + g*8);
#pragma unroll
        for (int n = 0; n < 2; n++) bfr[n] = *(const bf16x8*)(Bs[cur] + (wave*32 + n*16 + r)*32 + g*8);
#pragma unroll
        for (int m = 0; m < 4; m++)
#pragma unroll
            for (int n = 0; n < 2; n++)
                acc[m][n] = __builtin_amdgcn_mfma_f32_16x16x32_bf16(af[m], bfr[n], acc[m][n], 0, 0, 0);
        asm volatile("s_waitcnt lgkmcnt(0)" ::: "memory");
        __builtin_amdgcn_s_barrier();
    }
#undef GO_STAGE

#pragma unroll
    for (int m = 0; m < 4; m++) {
#pragma unroll
        for (int n = 0; n < 2; n++) {
            int col = tile_n + wave*32 + n*16 + r;
            float bv = bias[col];
#pragma unroll
            for (int j = 0; j < 4; j++) {
                int row = tile_m + m*16 + g*4 + j;
                out[(size_t)row * DMODEL + col] = acc[m][n][j] + bv;
            }
        }
    }
}

// ---------------- flash attention (R12 exact: best measured 43.8us) ----------
// K/V tiles in LDS [64][64] bf16, both-sides XOR-swizzled (elem ^= (row&7)<<3).
// Reg-prefetch dbuf; l-sums via 4 extra MFMA against ones (acc_l rows = o32).
#define QBLK 128
#define KVB 64

static __device__ __forceinline__ void attn_tile_body(
        const bf16* Ks, const bf16* VsT,
        const bf16x8 qa2[4], const bf16x8& ones,
        f32x16 o32[2], f32x16& acc_l,
        int kv0, int qb, int qrow, int l31, int hi, int lane) {
    const f32x16 z16 = {0,0,0,0,0,0,0,0,0,0,0,0,0,0,0,0};
    int sw = (l31 & 7) << 3;
    f32x16 st[2];
    st[0] = z16; st[1] = z16;
    __builtin_amdgcn_s_setprio(1);
#pragma unroll
    for (int rb = 0; rb < 2; rb++) {
#pragma unroll
        for (int c = 0; c < 4; c++) {
            bf16x8 kf = ld_b8(Ks + ((((rb*32 + l31)*64) + c*16 + hi*8) ^ sw));
            st[rb] = __builtin_amdgcn_mfma_f32_32x32x16_bf16(kf, qa2[c], st[rb], 0, 0, 0);
        }
    }
    __builtin_amdgcn_s_setprio(0);

    bf16x8 vf[2][4];
#pragma unroll
    for (int dblk = 0; dblk < 2; dblk++)
#pragma unroll
        for (int c = 0; c < 4; c++)
            vf[dblk][c] = ld_b8(VsT + ((((dblk*32 + l31)*64) + c*16 + hi*8) ^ sw));

    bool needm = (kv0 + KVB - 1) > qb;
#pragma unroll
    for (int rb = 0; rb < 2; rb++) {
#pragma unroll
        for (int reg = 0; reg < 16; reg++) {
            float e = __builtin_amdgcn_exp2f(st[rb][reg]);
            if (needm) {
                int kv = kv0 + rb*32 + (reg & 3) + 8*(reg >> 2) + 4*hi;
                if (kv > qrow) e = 0.f;
            }
            st[rb][reg] = e;
        }
    }

    bf16x8 pa[4];
#pragma unroll
    for (int c = 0; c < 4; c++) {
        const f32x16& pp = st[c >> 1];
        const int base = (c & 1) * 8;
        uint32_t a0 = pk_bf16(pp[base+0], pp[base+1]);
        uint32_t a1 = pk_bf16(pp[base+2], pp[base+3]);
        uint32_t b0 = pk_bf16(pp[base+4], pp[base+5]);
        uint32_t b1 = pk_bf16(pp[base+6], pp[base+7]);
        u32x2 s0 = lane_swap32(a0, b0, lane);
        u32x2 s1 = lane_swap32(a1, b1, lane);
        uint4 fr = {s0.x, s1.x, s0.y, s1.y};
        pa[c] = __builtin_bit_cast(bf16x8, fr);
    }

    __builtin_amdgcn_s_setprio(1);
#pragma unroll
    for (int dblk = 0; dblk < 2; dblk++)
#pragma unroll
        for (int c = 0; c < 4; c++)
            o32[dblk] = __builtin_amdgcn_mfma_f32_32x32x16_bf16(pa[c], vf[dblk][c], o32[dblk], 0, 0, 0);
#pragma unroll
    for (int c = 0; c < 4; c++)
        acc_l = __builtin_amdgcn_mfma_f32_32x32x16_bf16(pa[c], ones, acc_l, 0, 0, 0);
    __builtin_amdgcn_s_setprio(0);
}

// ---- equal-length job tables ----
__device__ const int8_t JQC[32]  = {10,10, 4, 0, 15,15, 3, 1,  9, 9, 7, 2, 13,14, 7, 5,
                                    14,14,11, 5, 15, 8,11, 6,  8,12,12, 6, 13,13,11,12};
__device__ const int8_t JT0[32]  = { 0,11, 0, 0,  0,11, 0, 0,  0,10, 0, 0,  0, 0, 8, 0,
                                    10,20, 0, 6, 22, 0, 8, 0,  9, 0, 9, 7, 10,19,16,18};
__device__ const int8_t JT1[32]  = {11,22,10, 2, 11,22, 8, 4, 10,20, 8, 6, 10,10,16, 6,
                                    20,30, 8,12, 32, 9,16, 7, 18, 9,18,14, 19,28,24,26};
__device__ const int8_t JSEG[32] = { 0, 1, 0, 0,  0, 1, 0, 0,  0, 1, 0, 0,  0, 0, 1, 0,
                                     1, 2, 0, 1,  2, 0, 1, 0,  1, 0, 1, 1,  1, 2, 2, 2};

__global__ __launch_bounds__(256) void k_attn_split(
        const bf16* __restrict__ Q, const bf16* __restrict__ K,
        const bf16* __restrict__ Vt,
        bf16* __restrict__ Op0, bf16* __restrict__ Op1, bf16* __restrict__ Op2,
        float* __restrict__ Lp0, float* __restrict__ Lp1, float* __restrict__ Lp2) {
    int scu = blockIdx.x;
    int bh = scu >> 3, slot = scu & 7;
    int j = slot * 4 + blockIdx.y;
    int qc  = JQC[j];
    int t0  = JT0[j];
    int t1  = JT1[j];
    int seg = JSEG[j];
    int q0 = qc * QBLK;
    int tid = threadIdx.x, wave = tid >> 6, lane = tid & 63;
    int l31 = lane & 31, hi = lane >> 5;

    __shared__ __align__(16) bf16 Ks[2][KVB*64];
    __shared__ __align__(16) bf16 VsT[2][KVB*64];

    const bf16* Kg = K  + (size_t)bh * SEQ * DHEAD;
    const bf16* Vg = Vt + (size_t)bh * DHEAD * SEQ;

    int qb = q0 + wave * 32;
    int qrow = qb + l31;

    const bf16* qrow_p = Q + ((size_t)bh * SEQ + qrow) * DHEAD;
    bf16x8 qa2[4];
#pragma unroll
    for (int c = 0; c < 4; c++) qa2[c] = ld_b8(qrow_p + c*16 + hi*8);

    bf16x8 ones;
#pragma unroll
    for (int c = 0; c < 8; c++) ones[c] = (bf16)1.0f;

    const f32x16 z16 = {0,0,0,0,0,0,0,0,0,0,0,0,0,0,0,0};
    f32x16 o32[2], acc_l;
    o32[0] = z16; o32[1] = z16; acc_l = z16;

    int qmax_wave = qb + 31;

    int srow = tid >> 3, sc8 = tid & 7;
    int sw_st = (srow & 7) << 3;
    int wK0 = ((srow*64)      + sc8*8) ^ sw_st;
    int wK1 = (((srow+32)*64) + sc8*8) ^ sw_st;

    bf16x8 kreg[2], vreg[2];
    {
        int kvs = t0 * KVB;
        kreg[0] = ld_b8(Kg + (size_t)(kvs + srow)      * DHEAD + sc8*8);
        kreg[1] = ld_b8(Kg + (size_t)(kvs + srow + 32) * DHEAD + sc8*8);
        vreg[0] = ld_b8(Vg + (size_t)srow      * SEQ + kvs + sc8*8);
        vreg[1] = ld_b8(Vg + (size_t)(srow+32) * SEQ + kvs + sc8*8);
    }

    int cur = 0;
    for (int t = t0; t < t1; t++) {
        int kv0 = t * KVB;
        *(uint4*)&Ks[cur][wK0]  = __builtin_bit_cast(uint4, kreg[0]);
        *(uint4*)&Ks[cur][wK1]  = __builtin_bit_cast(uint4, kreg[1]);
        *(uint4*)&VsT[cur][wK0] = __builtin_bit_cast(uint4, vreg[0]);
        *(uint4*)&VsT[cur][wK1] = __builtin_bit_cast(uint4, vreg[1]);
        __syncthreads();

        if (t + 1 < t1) {
            int kv1 = kv0 + KVB;
            kreg[0] = ld_b8(Kg + (size_t)(kv1 + srow)      * DHEAD + sc8*8);
            kreg[1] = ld_b8(Kg + (size_t)(kv1 + srow + 32) * DHEAD + sc8*8);
            vreg[0] = ld_b8(Vg + (size_t)srow      * SEQ + kv1 + sc8*8);
            vreg[1] = ld_b8(Vg + (size_t)(srow+32) * SEQ + kv1 + sc8*8);
        }

        if (kv0 <= qmax_wave)
            attn_tile_body(Ks[cur], VsT[cur], qa2, ones, o32, acc_l,
                           kv0, qb, qrow, l31, hi, lane);
        cur ^= 1;
    }

    bf16* Op; float* Lp; size_t obase; int lbase;
    if (seg == 0)      { Op = Op0; Lp = Lp0; obase = ((size_t)bh*2048 + q0) * 64;          lbase = bh*2048 + q0; }
    else if (seg == 1) { Op = Op1; Lp = Lp1; obase = ((size_t)bh*1408 + (qc-5)*128) * 64;  lbase = bh*1408 + (qc-5)*128; }
    else               { Op = Op2; Lp = Lp2; obase = ((size_t)bh*640  + (qc-11)*128) * 64; lbase = bh*640  + (qc-11)*128; }

    if (l31 == 0) {
#pragma unroll
        for (int reg = 0; reg < 16; reg++) {
            int qr = (reg & 3) + 8*(reg >> 2) + 4*hi;
            Lp[lbase + wave*32 + qr] = acc_l[reg];
        }
    }

#pragma unroll
    for (int reg = 0; reg < 16; reg++) {
        int qr = (reg & 3) + 8*(reg >> 2) + 4*hi;
        size_t base = obase + (size_t)(wave*32 + qr) * 64 + l31;
        Op[base]      = (bf16)o32[0][reg];
        Op[base + 32] = (bf16)o32[1][reg];
    }
}

// ---- merge ----
__global__ __launch_bounds__(256) void k_merge(
        const bf16* __restrict__ Op0, const bf16* __restrict__ Op1,
        const bf16* __restrict__ Op2,
        const float* __restrict__ Lp0, const float* __restrict__ Lp1,
        const float* __restrict__ Lp2,
        bf16* __restrict__ Oa) {
    int g = blockIdx.x * 256 + threadIdx.x;      // 524288 total
    int dseg = g & 7;
    int s = (g >> 3) & 2047;
    int bh = g >> 14;
    int qc = s >> 7;
    int sl = s & 127;

    size_t r0 = ((size_t)bh * 2048 + s) * 64 + dseg*8;
    bf16x8 p0 = ld_b8(Op0 + r0);
    float l = Lp0[bh*2048 + s];
    float acc[8];
#pragma unroll
    for (int i = 0; i < 8; i++) acc[i] = (float)p0[i];

    if (qc >= 5) {
        size_t r1 = ((size_t)bh * 1408 + (qc-5)*128 + sl) * 64 + dseg*8;
        bf16x8 p1 = ld_b8(Op1 + r1);
        l += Lp1[bh*1408 + (qc-5)*128 + sl];
#pragma unroll
        for (int i = 0; i < 8; i++) acc[i] += (float)p1[i];
        if (qc >= 11) {
            size_t r2 = ((size_t)bh * 640 + (qc-11)*128 + sl) * 64 + dseg*8;
            bf16x8 p2 = ld_b8(Op2 + r2);
            l += Lp2[bh*640 + (qc-11)*128 + sl];
#pragma unroll
            for (int i = 0; i < 8; i++) acc[i] += (float)p2[i];
        }
    }

    float inv = 1.0f / l;
    bf16x8 r;
#pragma unroll
    for (int i = 0; i < 8; i++) r[i] = (bf16)(acc[i] * inv);
    int b = bh >> 4, h = bh & 15;
    *(uint4*)&Oa[(((size_t)b * SEQ + s) * NH + h) * DHEAD + dseg*8] =
        __builtin_bit_cast(uint4, r);
}

// ---- fallback single-pass attention for small ws (R12) ----
__global__ __launch_bounds__(256) void k_attn(
        const bf16* __restrict__ Q, const bf16* __restrict__ K,
        const bf16* __restrict__ Vt, bf16* __restrict__ O) {
    int bh = blockIdx.y;
    int qc = (bh >= 16) ? (15 - (int)blockIdx.x) : (int)blockIdx.x;
    int q0 = qc * QBLK;
    int tid = threadIdx.x, wave = tid >> 6, lane = tid & 63;
    int l31 = lane & 31, hi = lane >> 5;

    __shared__ __align__(16) bf16 Ks[2][KVB*64];
    __shared__ __align__(16) bf16 VsT[2][KVB*64];

    const bf16* Kg = K  + (size_t)bh * SEQ * DHEAD;
    const bf16* Vg = Vt + (size_t)bh * DHEAD * SEQ;

    int qb = q0 + wave * 32;
    int qrow = qb + l31;

    const bf16* qrow_p = Q + ((size_t)bh * SEQ + qrow) * DHEAD;
    bf16x8 qa2[4];
#pragma unroll
    for (int c = 0; c < 4; c++) qa2[c] = ld_b8(qrow_p + c*16 + hi*8);

    bf16x8 ones;
#pragma unroll
    for (int c = 0; c < 8; c++) ones[c] = (bf16)1.0f;

    const f32x16 z16 = {0,0,0,0,0,0,0,0,0,0,0,0,0,0,0,0};
    f32x16 o32[2], acc_l;
    o32[0] = z16; o32[1] = z16; acc_l = z16;

    int nt = 2*qc + 2;
    int qmax_wave = qb + 31;

    int srow = tid >> 3, sc8 = tid & 7;
    int sw_st = (srow & 7) << 3;
    int wK0 = ((srow*64)      + sc8*8) ^ sw_st;
    int wK1 = (((srow+32)*64) + sc8*8) ^ sw_st;

    bf16x8 kreg[2], vreg[2];
    kreg[0] = ld_b8(Kg + (size_t)srow      * DHEAD + sc8*8);
    kreg[1] = ld_b8(Kg + (size_t)(srow+32) * DHEAD + sc8*8);
    vreg[0] = ld_b8(Vg + (size_t)srow      * SEQ + sc8*8);
    vreg[1] = ld_b8(Vg + (size_t)(srow+32) * SEQ + sc8*8);

    int cur = 0;
    for (int t = 0; t < nt; t++) {
        int kv0 = t * KVB;
        *(uint4*)&Ks[cur][wK0]  = __builtin_bit_cast(uint4, kreg[0]);
        *(uint4*)&Ks[cur][wK1]  = __builtin_bit_cast(uint4, kreg[1]);
        *(uint4*)&VsT[cur][wK0] = __builtin_bit_cast(uint4, vreg[0]);
        *(uint4*)&VsT[cur][wK1] = __builtin_bit_cast(uint4, vreg[1]);
        __syncthreads();

        if (t + 1 < nt) {
            int kv1 = kv0 + KVB;
            kreg[0] = ld_b8(Kg + (size_t)(kv1 + srow)      * DHEAD + sc8*8);
            kreg[1] = ld_b8(Kg + (size_t)(kv1 + srow + 32) * DHEAD + sc8*8);
            vreg[0] = ld_b8(Vg + (size_t)srow      * SEQ + kv1 + sc8*8);
            vreg[1] = ld_b8(Vg + (size_t)(srow+32) * SEQ + kv1 + sc8*8);
        }

        if (kv0 <= qmax_wave)
            attn_tile_body(Ks[cur], VsT[cur], qa2, ones, o32, acc_l,
                           kv0, qb, qrow, l31, hi, lane);
        cur ^= 1;
    }

    int b = bh >> 4, h = bh & 15;
#pragma unroll
    for (int reg = 0; reg < 16; reg++) {
        int qr = (reg & 3) + 8*(reg >> 2) + 4*hi;
        int srow2 = q0 + wave*32 + qr;
        float linv = 1.0f / acc_l[reg];
        size_t base = (((size_t)b * SEQ + srow2) * NH + h) * DHEAD + l31;
        O[base]      = (bf16)(o32[0][reg] * linv);
        O[base + 32] = (bf16)(o32[1][reg] * linv);
    }
}

// ---------------- launch ----------------

extern "C" void kernel_launch(void* const* d_in, const int* in_sizes, int n_in,
                              void* d_out, int out_size, void* d_ws, size_t ws_size,
                              hipStream_t stream) {
    const float* x     = (const float*)d_in[0];
    const float* w_qkv = (const float*)d_in[1];
    const float* b_qkv = (const float*)d_in[2];
    const float* w_out = (const float*)d_in[3];
    const float* b_out = (const float*)d_in[4];
    float* out = (float*)d_out;

    char* ws = (char*)d_ws;
    bf16* xb   = (bf16*)(ws);                      // 8.39MB; later attn output
    bf16* wqkT = (bf16*)(ws + 8388608);            // 6.29MB (dead after GEMM1 -> Lp)
    bf16* woT  = (bf16*)(ws + 14680064);           // 2.10MB
    bf16* qb   = (bf16*)(ws + 16777216);           // 8.39MB
    bf16* kb   = (bf16*)(ws + 25165824);           // 8.39MB
    bf16* vb   = (bf16*)(ws + 33554432);           // 8.39MB (V^T layout)
    bf16* Op0  = (bf16*)(ws + 41943040);           // 8.39MB (seg0, all qc)
    bf16* Op1  = (bf16*)(ws + 50331648);           // 5.77MB (seg1, qc>=5)
    bf16* Op2  = (bf16*)(ws + 56098816);           // 2.62MB (seg2, qc>=11)
    float* Lp0 = (float*)(ws + 8388608);           // in dead wqkT region
    float* Lp1 = (float*)(ws + 8388608 + 262144);
    float* Lp2 = (float*)(ws + 8388608 + 524288);
    const size_t WS_NEED = 58720256;
    bf16* attn = xb;                               // reuse x_bf16 region

    k_cvt<<<(MROWS*DMODEL/4 + 255)/256, 256, 0, stream>>>(x, xb, MROWS*DMODEL/4);
    dim3 tb(32, 8);
    k_tcvt_qkv<<<dim3(NQKV/32, DMODEL/32), tb, 0, stream>>>(w_qkv, wqkT);
    k_tcvt<<<dim3(DMODEL/32, DMODEL/32), tb, 0, stream>>>(w_out, woT, DMODEL, DMODEL);

    k_gemm_qkv<<<dim3(12, 16), 512, 0, stream>>>(xb, wqkT, b_qkv, qb, kb, vb);

    if (ws_size >= WS_NEED) {
        k_attn_split<<<dim3(256, 4), 256, 0, stream>>>(qb, kb, vb,
                                                       Op0, Op1, Op2, Lp0, Lp1, Lp2);
        k_merge<<<(NBS*NH*SEQ*DHEAD/8)/256, 256, 0, stream>>>(Op0, Op1, Op2,
                                                              Lp0, Lp1, Lp2, attn);
    } else {
        k_attn<<<dim3(SEQ/QBLK, NBS*NH), 256, 0, stream>>>(qb, kb, vb, attn);
    }

    k_gemm_out<<<dim3(DMODEL/128, MROWS/64), 256, 0, stream>>>(attn, woT, b_out, out);
}

// Round 16
// 115.108 us; speedup vs baseline: 1.1542x; 1.0692x over previous
//
#include <hip/hip_runtime.h>
#include <hip/hip_bf16.h>
#include <stdint.h>

#define NBS 2
#define SEQ 2048
#define DMODEL 1024
#define NH 16
#define DHEAD 64
#define MROWS (NBS*SEQ)     // 4096
#define NQKV (NH*3*DHEAD)   // 3072

typedef __bf16 bf16;
typedef __bf16 bf16x8 __attribute__((ext_vector_type(8)));
typedef float f32x4 __attribute__((ext_vector_type(4)));
typedef float f32x16 __attribute__((ext_vector_type(16)));
typedef unsigned int u32x2 __attribute__((ext_vector_type(2)));

#define LOG2E 1.44269504088896f
#define QSCALE (0.125f * LOG2E)

static __device__ __forceinline__ void gload_lds16(const bf16* g, bf16* l) {
    __builtin_amdgcn_global_load_lds(
        (const __attribute__((address_space(1))) uint32_t*)g,
        (__attribute__((address_space(3))) uint32_t*)l, 16, 0, 0);
}

static __device__ __forceinline__ bf16x8 ld_b8(const bf16* p) {
    return __builtin_bit_cast(bf16x8, *(const uint4*)p);
}

static __device__ __forceinline__ uint32_t pk_bf16(float lo, float hi) {
    unsigned short l = __builtin_bit_cast(unsigned short, (bf16)lo);
    unsigned short h = __builtin_bit_cast(unsigned short, (bf16)hi);
    return ((uint32_t)h << 16) | (uint32_t)l;
}

static __device__ __forceinline__ u32x2 lane_swap32(uint32_t a, uint32_t b, int lane) {
#if __has_builtin(__builtin_amdgcn_permlane32_swap)
    return __builtin_amdgcn_permlane32_swap(a, b, false, false);
#else
    uint32_t sa = __shfl_xor(a, 32), sb = __shfl_xor(b, 32);
    u32x2 r;
    r.x = (lane >= 32) ? sb : a;
    r.y = (lane >= 32) ? b : sa;
    return r;
#endif
}

// ---------------- fused prep: x->bf16, w_qkv permuted-T, w_out T ----------------
// grid: [0,4096) = x cvt; [4096,7168) = w_qkv tcvt; [7168,8192) = w_out tcvt.
__global__ __launch_bounds__(256) void k_prep(
        const float* __restrict__ x, const float* __restrict__ w_qkv,
        const float* __restrict__ w_out,
        bf16* __restrict__ xb, bf16* __restrict__ wqkT, bf16* __restrict__ woT) {
    __shared__ float t[32][33];
    int bid = blockIdx.x, tid = threadIdx.x;
    if (bid < 4096) {
        int i = bid * 256 + tid;
        float4 v = ((const float4*)x)[i];
        ushort4 o;
        o.x = __builtin_bit_cast(unsigned short, (bf16)v.x);
        o.y = __builtin_bit_cast(unsigned short, (bf16)v.y);
        o.z = __builtin_bit_cast(unsigned short, (bf16)v.z);
        o.w = __builtin_bit_cast(unsigned short, (bf16)v.w);
        ((ushort4*)xb)[i] = o;
    } else if (bid < 7168) {
        int lb = bid - 4096;
        int bx = lb % 96, by = lb / 96;        // (NQKV/32, DMODEL/32)
        int tx = tid & 31, ty = tid >> 5;
        int r0 = by * 32, c0 = bx * 32;
#pragma unroll
        for (int i = 0; i < 4; i++)
            t[ty + i*8][tx] = w_qkv[(size_t)(r0 + ty + i*8) * NQKV + (c0 + tx)];
        __syncthreads();
#pragma unroll
        for (int i = 0; i < 4; i++) {
            int c = c0 + ty + i*8;
            int h = c / 192, f = c % 192;
            int cperm = ((f >> 6) << 10) + (h << 6) + (f & 63);
            wqkT[(size_t)cperm * DMODEL + (r0 + tx)] = (bf16)t[tx][ty + i*8];
        }
    } else {
        int lb = bid - 7168;
        int bx = lb & 31, by = lb >> 5;        // (DMODEL/32, DMODEL/32)
        int tx = tid & 31, ty = tid >> 5;
        int r0 = by * 32, c0 = bx * 32;
#pragma unroll
        for (int i = 0; i < 4; i++)
            t[ty + i*8][tx] = w_out[(size_t)(r0 + ty + i*8) * DMODEL + (c0 + tx)];
        __syncthreads();
#pragma unroll
        for (int i = 0; i < 4; i++)
            woT[(size_t)(c0 + ty + i*8) * DMODEL + (r0 + tx)] = (bf16)t[tx][ty + i*8];
    }
}

// ---------------- GEMM1: 256x192 tile, BK=64, 512 thr, counted-vmcnt ----------
// Grid 16x16 = 256 blocks -> every CU busy (R12 was 192 blocks / 64 CUs idle).
// 8 waves (2M x 4N): per-wave 128x48 = acc[8][3]. LDS (256+192)*64*2B*2 = 112KB.
#define G1_NT 16   // 1024/64 K-tiles

__global__ __launch_bounds__(512, 2) void k_gemm_qkv(
        const bf16* __restrict__ A, const bf16* __restrict__ Bt,
        const float* __restrict__ bias,
        bf16* __restrict__ Q, bf16* __restrict__ Kp, bf16* __restrict__ Vt) {
    __shared__ __align__(16) bf16 As[2][256*64];
    __shared__ __align__(16) bf16 Bs[2][192*64];
    int tid = threadIdx.x;
    int wid = tid >> 6, lane = tid & 63;
    int wr = wid >> 2, wc = wid & 3;
    int g = lane >> 4, r = lane & 15;

    // XCD swizzle: 256 blocks, 32 per XCD
    int lid = blockIdx.y * 16 + blockIdx.x;
    int swz = (lid & 7) * 32 + (lid >> 3);
    int tile_n = (swz % 16) * 192, tile_m = (swz / 16) * 256;

    f32x4 acc[8][3];
#pragma unroll
    for (int m = 0; m < 8; m++)
#pragma unroll
        for (int n = 0; n < 3; n++)
            acc[m][n] = (f32x4){0.f, 0.f, 0.f, 0.f};

    int srowA[4], schkA[4], srowB[3], schkB[3];
#pragma unroll
    for (int j2 = 0; j2 < 4; j2++) {
        int idx = tid + j2 * 512;
        srowA[j2] = idx >> 3;
        schkA[j2] = ((idx & 7) ^ (srowA[j2] & 7)) * 8;
    }
#pragma unroll
    for (int j2 = 0; j2 < 3; j2++) {
        int idx = tid + j2 * 512;
        srowB[j2] = idx >> 3;
        schkB[j2] = ((idx & 7) ^ (srowB[j2] & 7)) * 8;
    }

#define G1_STAGE(buf, k0)                                                          \
    {                                                                              \
        _Pragma("unroll")                                                          \
        for (int j2 = 0; j2 < 4; j2++)                                             \
            gload_lds16(A + (size_t)(tile_m + srowA[j2]) * DMODEL + (k0) + schkA[j2], \
                        As[buf] + (tid + j2*512) * 8);                             \
        _Pragma("unroll")                                                          \
        for (int j2 = 0; j2 < 3; j2++)                                             \
            gload_lds16(Bt + (size_t)(tile_n + srowB[j2]) * DMODEL + (k0) + schkB[j2], \
                        Bs[buf] + (tid + j2*512) * 8);                             \
    }

    G1_STAGE(0, 0);

    int r7 = r & 7;
    for (int t = 0; t < G1_NT; t++) {
        int cur = t & 1;
        if (t + 1 < G1_NT) {
            G1_STAGE(cur ^ 1, (t + 1) * 64);
            asm volatile("s_waitcnt vmcnt(7)" ::: "memory");
        } else {
            asm volatile("s_waitcnt vmcnt(0)" ::: "memory");
        }
        __builtin_amdgcn_s_barrier();
        __builtin_amdgcn_sched_barrier(0);

        const bf16* pa = As[cur];
        const bf16* pb = Bs[cur];
#pragma unroll
        for (int kk = 0; kk < 2; kk++) {
            int rchk = ((kk*4 + g) ^ r7) * 8;
            bf16x8 bfr[3];
#pragma unroll
            for (int n = 0; n < 3; n++)
                bfr[n] = ld_b8(pb + (wc*48 + n*16 + r) * 64 + rchk);
#pragma unroll
            for (int m = 0; m < 8; m++) {
                bf16x8 af = ld_b8(pa + (wr*128 + m*16 + r) * 64 + rchk);
#pragma unroll
                for (int n = 0; n < 3; n++)
                    acc[m][n] = __builtin_amdgcn_mfma_f32_16x16x32_bf16(af, bfr[n], acc[m][n], 0, 0, 0);
            }
        }
        asm volatile("s_waitcnt lgkmcnt(0)" ::: "memory");
        __builtin_amdgcn_s_barrier();
    }

    // epilogue: permuted cols -> kind*1024 + h*64 + d (kind,h,d-base uniform/frag)
#pragma unroll
    for (int m = 0; m < 8; m++) {
#pragma unroll
        for (int n = 0; n < 3; n++) {
            int col = tile_n + wc*48 + n*16 + r;
            int kind = col >> 10;
            int h = (col >> 6) & 15;
            int d = col & 63;
            float bv = bias[h*192 + (kind << 6) + d];
            if (kind == 2) {
                int row0 = tile_m + wr*128 + m*16 + g*4;
                int b = row0 >> 11, s0 = row0 & 2047;
                ushort4 vv;
                vv.x = __builtin_bit_cast(unsigned short, (bf16)(acc[m][n][0] + bv));
                vv.y = __builtin_bit_cast(unsigned short, (bf16)(acc[m][n][1] + bv));
                vv.z = __builtin_bit_cast(unsigned short, (bf16)(acc[m][n][2] + bv));
                vv.w = __builtin_bit_cast(unsigned short, (bf16)(acc[m][n][3] + bv));
                *(ushort4*)&Vt[(((size_t)(b*NH + h)) * DHEAD + d) * SEQ + s0] = vv;
            } else {
#pragma unroll
                for (int j = 0; j < 4; j++) {
                    int row = tile_m + wr*128 + m*16 + g*4 + j;
                    int b = row >> 11, s = row & 2047;
                    float v = acc[m][n][j] + bv;
                    size_t addr = (((size_t)(b*NH + h)) * SEQ + s) * DHEAD + d;
                    if (kind == 0) Q[addr]  = (bf16)(v * QSCALE);
                    else           Kp[addr] = (bf16)v;
                }
            }
        }
    }
#undef G1_STAGE
}

// ---- gemm_out: 64x128 tile, dbuf + counted vmcnt, grid 512 = 2/CU (R15) ----
__global__ __launch_bounds__(256) void k_gemm_out(
        const bf16* __restrict__ A, const bf16* __restrict__ Bt,
        const float* __restrict__ bias, float* __restrict__ out) {
    __shared__ __align__(16) bf16 As[2][64*32];
    __shared__ __align__(16) bf16 Bs[2][128*32];
    int tid = threadIdx.x;
    int wave = tid >> 6, lane = tid & 63;
    int g = lane >> 4, r = lane & 15;
    int srow = lane >> 2, schunk = (lane & 3) * 8;
    int tile_m = blockIdx.y * 64, tile_n = blockIdx.x * 128;

    f32x4 acc[4][2];
#pragma unroll
    for (int m = 0; m < 4; m++)
#pragma unroll
        for (int n = 0; n < 2; n++)
            acc[m][n] = (f32x4){0.f, 0.f, 0.f, 0.f};

#define GO_STAGE(buf, k0)                                                                 \
    {                                                                                     \
        gload_lds16(A  + (size_t)(tile_m + wave*16 + srow) * DMODEL + (k0) + schunk,      \
                    As[buf] + wave*512);                                                  \
        gload_lds16(Bt + (size_t)(tile_n + wave*16 + srow) * DMODEL + (k0) + schunk,      \
                    Bs[buf] + wave*512);                                                  \
        gload_lds16(Bt + (size_t)(tile_n + 64 + wave*16 + srow) * DMODEL + (k0) + schunk, \
                    Bs[buf] + 2048 + wave*512);                                           \
    }

    GO_STAGE(0, 0);

    for (int t = 0; t < 32; t++) {
        int cur = t & 1;
        if (t + 1 < 32) {
            GO_STAGE(cur ^ 1, (t + 1) * 32);
            asm volatile("s_waitcnt vmcnt(3)" ::: "memory");
        } else {
            asm volatile("s_waitcnt vmcnt(0)" ::: "memory");
        }
        __builtin_amdgcn_s_barrier();
        __builtin_amdgcn_sched_barrier(0);

        bf16x8 af[4], bfr[2];
#pragma unroll
        for (int m = 0; m < 4; m++) af[m]  = *(const bf16x8*)(As[cur] + (m*16 + r)*32 + g*8);
#pragma unroll
        for (int n = 0; n < 2; n++) bfr[n] = *(const bf16x8*)(Bs[cur] + (wave*32 + n*16 + r)*32 + g*8);
#pragma unroll
        for (int m = 0; m < 4; m++)
#pragma unroll
            for (int n = 0; n < 2; n++)
                acc[m][n] = __builtin_amdgcn_mfma_f32_16x16x32_bf16(af[m], bfr[n], acc[m][n], 0, 0, 0);
        asm volatile("s_waitcnt lgkmcnt(0)" ::: "memory");
        __builtin_amdgcn_s_barrier();
    }
#undef GO_STAGE

#pragma unroll
    for (int m = 0; m < 4; m++) {
#pragma unroll
        for (int n = 0; n < 2; n++) {
            int col = tile_n + wave*32 + n*16 + r;
            float bv = bias[col];
#pragma unroll
            for (int j = 0; j < 4; j++) {
                int row = tile_m + m*16 + g*4 + j;
                out[(size_t)row * DMODEL + col] = acc[m][n][j] + bv;
            }
        }
    }
}

// ---------------- flash attention (R12 exact: best measured 43.8us) ----------
#define QBLK 128
#define KVB 64

static __device__ __forceinline__ void attn_tile_body(
        const bf16* Ks, const bf16* VsT,
        const bf16x8 qa2[4], const bf16x8& ones,
        f32x16 o32[2], f32x16& acc_l,
        int kv0, int qb, int qrow, int l31, int hi, int lane) {
    const f32x16 z16 = {0,0,0,0,0,0,0,0,0,0,0,0,0,0,0,0};
    int sw = (l31 & 7) << 3;
    f32x16 st[2];
    st[0] = z16; st[1] = z16;
    __builtin_amdgcn_s_setprio(1);
#pragma unroll
    for (int rb = 0; rb < 2; rb++) {
#pragma unroll
        for (int c = 0; c < 4; c++) {
            bf16x8 kf = ld_b8(Ks + ((((rb*32 + l31)*64) + c*16 + hi*8) ^ sw));
            st[rb] = __builtin_amdgcn_mfma_f32_32x32x16_bf16(kf, qa2[c], st[rb], 0, 0, 0);
        }
    }
    __builtin_amdgcn_s_setprio(0);

    bf16x8 vf[2][4];
#pragma unroll
    for (int dblk = 0; dblk < 2; dblk++)
#pragma unroll
        for (int c = 0; c < 4; c++)
            vf[dblk][c] = ld_b8(VsT + ((((dblk*32 + l31)*64) + c*16 + hi*8) ^ sw));

    bool needm = (kv0 + KVB - 1) > qb;
#pragma unroll
    for (int rb = 0; rb < 2; rb++) {
#pragma unroll
        for (int reg = 0; reg < 16; reg++) {
            float e = __builtin_amdgcn_exp2f(st[rb][reg]);
            if (needm) {
                int kv = kv0 + rb*32 + (reg & 3) + 8*(reg >> 2) + 4*hi;
                if (kv > qrow) e = 0.f;
            }
            st[rb][reg] = e;
        }
    }

    bf16x8 pa[4];
#pragma unroll
    for (int c = 0; c < 4; c++) {
        const f32x16& pp = st[c >> 1];
        const int base = (c & 1) * 8;
        uint32_t a0 = pk_bf16(pp[base+0], pp[base+1]);
        uint32_t a1 = pk_bf16(pp[base+2], pp[base+3]);
        uint32_t b0 = pk_bf16(pp[base+4], pp[base+5]);
        uint32_t b1 = pk_bf16(pp[base+6], pp[base+7]);
        u32x2 s0 = lane_swap32(a0, b0, lane);
        u32x2 s1 = lane_swap32(a1, b1, lane);
        uint4 fr = {s0.x, s1.x, s0.y, s1.y};
        pa[c] = __builtin_bit_cast(bf16x8, fr);
    }

    __builtin_amdgcn_s_setprio(1);
#pragma unroll
    for (int dblk = 0; dblk < 2; dblk++)
#pragma unroll
        for (int c = 0; c < 4; c++)
            o32[dblk] = __builtin_amdgcn_mfma_f32_32x32x16_bf16(pa[c], vf[dblk][c], o32[dblk], 0, 0, 0);
#pragma unroll
    for (int c = 0; c < 4; c++)
        acc_l = __builtin_amdgcn_mfma_f32_32x32x16_bf16(pa[c], ones, acc_l, 0, 0, 0);
    __builtin_amdgcn_s_setprio(0);
}

// ---- equal-length job tables ----
__device__ const int8_t JQC[32]  = {10,10, 4, 0, 15,15, 3, 1,  9, 9, 7, 2, 13,14, 7, 5,
                                    14,14,11, 5, 15, 8,11, 6,  8,12,12, 6, 13,13,11,12};
__device__ const int8_t JT0[32]  = { 0,11, 0, 0,  0,11, 0, 0,  0,10, 0, 0,  0, 0, 8, 0,
                                    10,20, 0, 6, 22, 0, 8, 0,  9, 0, 9, 7, 10,19,16,18};
__device__ const int8_t JT1[32]  = {11,22,10, 2, 11,22, 8, 4, 10,20, 8, 6, 10,10,16, 6,
                                    20,30, 8,12, 32, 9,16, 7, 18, 9,18,14, 19,28,24,26};
__device__ const int8_t JSEG[32] = { 0, 1, 0, 0,  0, 1, 0, 0,  0, 1, 0, 0,  0, 0, 1, 0,
                                     1, 2, 0, 1,  2, 0, 1, 0,  1, 0, 1, 1,  1, 2, 2, 2};

__global__ __launch_bounds__(256) void k_attn_split(
        const bf16* __restrict__ Q, const bf16* __restrict__ K,
        const bf16* __restrict__ Vt,
        bf16* __restrict__ Op0, bf16* __restrict__ Op1, bf16* __restrict__ Op2,
        float* __restrict__ Lp0, float* __restrict__ Lp1, float* __restrict__ Lp2) {
    int scu = blockIdx.x;
    int bh = scu >> 3, slot = scu & 7;
    int j = slot * 4 + blockIdx.y;
    int qc  = JQC[j];
    int t0  = JT0[j];
    int t1  = JT1[j];
    int seg = JSEG[j];
    int q0 = qc * QBLK;
    int tid = threadIdx.x, wave = tid >> 6, lane = tid & 63;
    int l31 = lane & 31, hi = lane >> 5;

    __shared__ __align__(16) bf16 Ks[2][KVB*64];
    __shared__ __align__(16) bf16 VsT[2][KVB*64];

    const bf16* Kg = K  + (size_t)bh * SEQ * DHEAD;
    const bf16* Vg = Vt + (size_t)bh * DHEAD * SEQ;

    int qb = q0 + wave * 32;
    int qrow = qb + l31;

    const bf16* qrow_p = Q + ((size_t)bh * SEQ + qrow) * DHEAD;
    bf16x8 qa2[4];
#pragma unroll
    for (int c = 0; c < 4; c++) qa2[c] = ld_b8(qrow_p + c*16 + hi*8);

    bf16x8 ones;
#pragma unroll
    for (int c = 0; c < 8; c++) ones[c] = (bf16)1.0f;

    const f32x16 z16 = {0,0,0,0,0,0,0,0,0,0,0,0,0,0,0,0};
    f32x16 o32[2], acc_l;
    o32[0] = z16; o32[1] = z16; acc_l = z16;

    int qmax_wave = qb + 31;

    int srow = tid >> 3, sc8 = tid & 7;
    int sw_st = (srow & 7) << 3;
    int wK0 = ((srow*64)      + sc8*8) ^ sw_st;
    int wK1 = (((srow+32)*64) + sc8*8) ^ sw_st;

    bf16x8 kreg[2], vreg[2];
    {
        int kvs = t0 * KVB;
        kreg[0] = ld_b8(Kg + (size_t)(kvs + srow)      * DHEAD + sc8*8);
        kreg[1] = ld_b8(Kg + (size_t)(kvs + srow + 32) * DHEAD + sc8*8);
        vreg[0] = ld_b8(Vg + (size_t)srow      * SEQ + kvs + sc8*8);
        vreg[1] = ld_b8(Vg + (size_t)(srow+32) * SEQ + kvs + sc8*8);
    }

    int cur = 0;
    for (int t = t0; t < t1; t++) {
        int kv0 = t * KVB;
        *(uint4*)&Ks[cur][wK0]  = __builtin_bit_cast(uint4, kreg[0]);
        *(uint4*)&Ks[cur][wK1]  = __builtin_bit_cast(uint4, kreg[1]);
        *(uint4*)&VsT[cur][wK0] = __builtin_bit_cast(uint4, vreg[0]);
        *(uint4*)&VsT[cur][wK1] = __builtin_bit_cast(uint4, vreg[1]);
        __syncthreads();

        if (t + 1 < t1) {
            int kv1 = kv0 + KVB;
            kreg[0] = ld_b8(Kg + (size_t)(kv1 + srow)      * DHEAD + sc8*8);
            kreg[1] = ld_b8(Kg + (size_t)(kv1 + srow + 32) * DHEAD + sc8*8);
            vreg[0] = ld_b8(Vg + (size_t)srow      * SEQ + kv1 + sc8*8);
            vreg[1] = ld_b8(Vg + (size_t)(srow+32) * SEQ + kv1 + sc8*8);
        }

        if (kv0 <= qmax_wave)
            attn_tile_body(Ks[cur], VsT[cur], qa2, ones, o32, acc_l,
                           kv0, qb, qrow, l31, hi, lane);
        cur ^= 1;
    }

    bf16* Op; float* Lp; size_t obase; int lbase;
    if (seg == 0)      { Op = Op0; Lp = Lp0; obase = ((size_t)bh*2048 + q0) * 64;          lbase = bh*2048 + q0; }
    else if (seg == 1) { Op = Op1; Lp = Lp1; obase = ((size_t)bh*1408 + (qc-5)*128) * 64;  lbase = bh*1408 + (qc-5)*128; }
    else               { Op = Op2; Lp = Lp2; obase = ((size_t)bh*640  + (qc-11)*128) * 64; lbase = bh*640  + (qc-11)*128; }

    if (l31 == 0) {
#pragma unroll
        for (int reg = 0; reg < 16; reg++) {
            int qr = (reg & 3) + 8*(reg >> 2) + 4*hi;
            Lp[lbase + wave*32 + qr] = acc_l[reg];
        }
    }

#pragma unroll
    for (int reg = 0; reg < 16; reg++) {
        int qr = (reg & 3) + 8*(reg >> 2) + 4*hi;
        size_t base = obase + (size_t)(wave*32 + qr) * 64 + l31;
        Op[base]      = (bf16)o32[0][reg];
        Op[base + 32] = (bf16)o32[1][reg];
    }
}

// ---- merge ----
__global__ __launch_bounds__(256) void k_merge(
        const bf16* __restrict__ Op0, const bf16* __restrict__ Op1,
        const bf16* __restrict__ Op2,
        const float* __restrict__ Lp0, const float* __restrict__ Lp1,
        const float* __restrict__ Lp2,
        bf16* __restrict__ Oa) {
    int g = blockIdx.x * 256 + threadIdx.x;      // 524288 total
    int dseg = g & 7;
    int s = (g >> 3) & 2047;
    int bh = g >> 14;
    int qc = s >> 7;
    int sl = s & 127;

    size_t r0 = ((size_t)bh * 2048 + s) * 64 + dseg*8;
    bf16x8 p0 = ld_b8(Op0 + r0);
    float l = Lp0[bh*2048 + s];
    float acc[8];
#pragma unroll
    for (int i = 0; i < 8; i++) acc[i] = (float)p0[i];

    if (qc >= 5) {
        size_t r1 = ((size_t)bh * 1408 + (qc-5)*128 + sl) * 64 + dseg*8;
        bf16x8 p1 = ld_b8(Op1 + r1);
        l += Lp1[bh*1408 + (qc-5)*128 + sl];
#pragma unroll
        for (int i = 0; i < 8; i++) acc[i] += (float)p1[i];
        if (qc >= 11) {
            size_t r2 = ((size_t)bh * 640 + (qc-11)*128 + sl) * 64 + dseg*8;
            bf16x8 p2 = ld_b8(Op2 + r2);
            l += Lp2[bh*640 + (qc-11)*128 + sl];
#pragma unroll
            for (int i = 0; i < 8; i++) acc[i] += (float)p2[i];
        }
    }

    float inv = 1.0f / l;
    bf16x8 r;
#pragma unroll
    for (int i = 0; i < 8; i++) r[i] = (bf16)(acc[i] * inv);
    int b = bh >> 4, h = bh & 15;
    *(uint4*)&Oa[(((size_t)b * SEQ + s) * NH + h) * DHEAD + dseg*8] =
        __builtin_bit_cast(uint4, r);
}

// ---- fallback single-pass attention for small ws (R12) ----
__global__ __launch_bounds__(256) void k_attn(
        const bf16* __restrict__ Q, const bf16* __restrict__ K,
        const bf16* __restrict__ Vt, bf16* __restrict__ O) {
    int bh = blockIdx.y;
    int qc = (bh >= 16) ? (15 - (int)blockIdx.x) : (int)blockIdx.x;
    int q0 = qc * QBLK;
    int tid = threadIdx.x, wave = tid >> 6, lane = tid & 63;
    int l31 = lane & 31, hi = lane >> 5;

    __shared__ __align__(16) bf16 Ks[2][KVB*64];
    __shared__ __align__(16) bf16 VsT[2][KVB*64];

    const bf16* Kg = K  + (size_t)bh * SEQ * DHEAD;
    const bf16* Vg = Vt + (size_t)bh * DHEAD * SEQ;

    int qb = q0 + wave * 32;
    int qrow = qb + l31;

    const bf16* qrow_p = Q + ((size_t)bh * SEQ + qrow) * DHEAD;
    bf16x8 qa2[4];
#pragma unroll
    for (int c = 0; c < 4; c++) qa2[c] = ld_b8(qrow_p + c*16 + hi*8);

    bf16x8 ones;
#pragma unroll
    for (int c = 0; c < 8; c++) ones[c] = (bf16)1.0f;

    const f32x16 z16 = {0,0,0,0,0,0,0,0,0,0,0,0,0,0,0,0};
    f32x16 o32[2], acc_l;
    o32[0] = z16; o32[1] = z16; acc_l = z16;

    int nt = 2*qc + 2;
    int qmax_wave = qb + 31;

    int srow = tid >> 3, sc8 = tid & 7;
    int sw_st = (srow & 7) << 3;
    int wK0 = ((srow*64)      + sc8*8) ^ sw_st;
    int wK1 = (((srow+32)*64) + sc8*8) ^ sw_st;

    bf16x8 kreg[2], vreg[2];
    kreg[0] = ld_b8(Kg + (size_t)srow      * DHEAD + sc8*8);
    kreg[1] = ld_b8(Kg + (size_t)(srow+32) * DHEAD + sc8*8);
    vreg[0] = ld_b8(Vg + (size_t)srow      * SEQ + sc8*8);
    vreg[1] = ld_b8(Vg + (size_t)(srow+32) * SEQ + sc8*8);

    int cur = 0;
    for (int t = 0; t < nt; t++) {
        int kv0 = t * KVB;
        *(uint4*)&Ks[cur][wK0]  = __builtin_bit_cast(uint4, kreg[0]);
        *(uint4*)&Ks[cur][wK1]  = __builtin_bit_cast(uint4, kreg[1]);
        *(uint4*)&VsT[cur][wK0] = __builtin_bit_cast(uint4, vreg[0]);
        *(uint4*)&VsT[cur][wK1] = __builtin_bit_cast(uint4, vreg[1]);
        __syncthreads();

        if (t + 1 < nt) {
            int kv1 = kv0 + KVB;
            kreg[0] = ld_b8(Kg + (size_t)(kv1 + srow)      * DHEAD + sc8*8);
            kreg[1] = ld_b8(Kg + (size_t)(kv1 + srow + 32) * DHEAD + sc8*8);
            vreg[0] = ld_b8(Vg + (size_t)srow      * SEQ + kv1 + sc8*8);
            vreg[1] = ld_b8(Vg + (size_t)(srow+32) * SEQ + kv1 + sc8*8);
        }

        if (kv0 <= qmax_wave)
            attn_tile_body(Ks[cur], VsT[cur], qa2, ones, o32, acc_l,
                           kv0, qb, qrow, l31, hi, lane);
        cur ^= 1;
    }

    int b = bh >> 4, h = bh & 15;
#pragma unroll
    for (int reg = 0; reg < 16; reg++) {
        int qr = (reg & 3) + 8*(reg >> 2) + 4*hi;
        int srow2 = q0 + wave*32 + qr;
        float linv = 1.0f / acc_l[reg];
        size_t base = (((size_t)b * SEQ + srow2) * NH + h) * DHEAD + l31;
        O[base]      = (bf16)(o32[0][reg] * linv);
        O[base + 32] = (bf16)(o32[1][reg] * linv);
    }
}

// ---------------- launch ----------------

extern "C" void kernel_launch(void* const* d_in, const int* in_sizes, int n_in,
                              void* d_out, int out_size, void* d_ws, size_t ws_size,
                              hipStream_t stream) {
    const float* x     = (const float*)d_in[0];
    const float* w_qkv = (const float*)d_in[1];
    const float* b_qkv = (const float*)d_in[2];
    const float* w_out = (const float*)d_in[3];
    const float* b_out = (const float*)d_in[4];
    float* out = (float*)d_out;

    char* ws = (char*)d_ws;
    bf16* xb   = (bf16*)(ws);                      // 8.39MB; later attn output
    bf16* wqkT = (bf16*)(ws + 8388608);            // 6.29MB (dead after GEMM1 -> Lp)
    bf16* woT  = (bf16*)(ws + 14680064);           // 2.10MB
    bf16* qb   = (bf16*)(ws + 16777216);           // 8.39MB
    bf16* kb   = (bf16*)(ws + 25165824);           // 8.39MB
    bf16* vb   = (bf16*)(ws + 33554432);           // 8.39MB (V^T layout)
    bf16* Op0  = (bf16*)(ws + 41943040);           // 8.39MB (seg0, all qc)
    bf16* Op1  = (bf16*)(ws + 50331648);           // 5.77MB (seg1, qc>=5)
    bf16* Op2  = (bf16*)(ws + 56098816);           // 2.62MB (seg2, qc>=11)
    float* Lp0 = (float*)(ws + 8388608);           // in dead wqkT region
    float* Lp1 = (float*)(ws + 8388608 + 262144);
    float* Lp2 = (float*)(ws + 8388608 + 524288);
    const size_t WS_NEED = 58720256;
    bf16* attn = xb;                               // reuse x_bf16 region

    k_prep<<<8192, 256, 0, stream>>>(x, w_qkv, w_out, xb, wqkT, woT);

    k_gemm_qkv<<<dim3(16, 16), 512, 0, stream>>>(xb, wqkT, b_qkv, qb, kb, vb);

    if (ws_size >= WS_NEED) {
        k_attn_split<<<dim3(256, 4), 256, 0, stream>>>(qb, kb, vb,
                                                       Op0, Op1, Op2, Lp0, Lp1, Lp2);
        k_merge<<<(NBS*NH*SEQ*DHEAD/8)/256, 256, 0, stream>>>(Op0, Op1, Op2,
                                                              Lp0, Lp1, Lp2, attn);
    } else {
        k_attn<<<dim3(SEQ/QBLK, NBS*NH), 256, 0, stream>>>(qb, kb, vb, attn);
    }

    k_gemm_out<<<dim3(DMODEL/128, MROWS/64), 256, 0, stream>>>(attn, woT, b_out, out);
}

// Round 17
// 115.045 us; speedup vs baseline: 1.1548x; 1.0005x over previous
//
#include <hip/hip_runtime.h>
#include <hip/hip_bf16.h>
#include <stdint.h>

#define NBS 2
#define SEQ 2048
#define DMODEL 1024
#define NH 16
#define DHEAD 64
#define MROWS (NBS*SEQ)     // 4096
#define NQKV (NH*3*DHEAD)   // 3072

typedef __bf16 bf16;
typedef __bf16 bf16x8 __attribute__((ext_vector_type(8)));
typedef float f32x4 __attribute__((ext_vector_type(4)));
typedef float f32x16 __attribute__((ext_vector_type(16)));
typedef unsigned int u32x2 __attribute__((ext_vector_type(2)));

#define LOG2E 1.44269504088896f
#define QSCALE (0.125f * LOG2E)
#define KSTR 72   // attn LDS row stride (pad: 144B, 16B-aligned, 0 conflicts @R5)

static __device__ __forceinline__ void gload_lds16(const bf16* g, bf16* l) {
    __builtin_amdgcn_global_load_lds(
        (const __attribute__((address_space(1))) uint32_t*)g,
        (__attribute__((address_space(3))) uint32_t*)l, 16, 0, 0);
}

static __device__ __forceinline__ bf16x8 ld_b8(const bf16* p) {
    return __builtin_bit_cast(bf16x8, *(const uint4*)p);
}

static __device__ __forceinline__ uint32_t pk_bf16(float lo, float hi) {
    unsigned short l = __builtin_bit_cast(unsigned short, (bf16)lo);
    unsigned short h = __builtin_bit_cast(unsigned short, (bf16)hi);
    return ((uint32_t)h << 16) | (uint32_t)l;
}

static __device__ __forceinline__ u32x2 lane_swap32(uint32_t a, uint32_t b, int lane) {
#if __has_builtin(__builtin_amdgcn_permlane32_swap)
    return __builtin_amdgcn_permlane32_swap(a, b, false, false);
#else
    uint32_t sa = __shfl_xor(a, 32), sb = __shfl_xor(b, 32);
    u32x2 r;
    r.x = (lane >= 32) ? sb : a;
    r.y = (lane >= 32) ? b : sa;
    return r;
#endif
}

// ---------------- fused prep: x->bf16, w_qkv permuted-T, w_out T ----------------
__global__ __launch_bounds__(256) void k_prep(
        const float* __restrict__ x, const float* __restrict__ w_qkv,
        const float* __restrict__ w_out,
        bf16* __restrict__ xb, bf16* __restrict__ wqkT, bf16* __restrict__ woT) {
    __shared__ float t[32][33];
    int bid = blockIdx.x, tid = threadIdx.x;
    if (bid < 4096) {
        int i = bid * 256 + tid;
        float4 v = ((const float4*)x)[i];
        ushort4 o;
        o.x = __builtin_bit_cast(unsigned short, (bf16)v.x);
        o.y = __builtin_bit_cast(unsigned short, (bf16)v.y);
        o.z = __builtin_bit_cast(unsigned short, (bf16)v.z);
        o.w = __builtin_bit_cast(unsigned short, (bf16)v.w);
        ((ushort4*)xb)[i] = o;
    } else if (bid < 7168) {
        int lb = bid - 4096;
        int bx = lb % 96, by = lb / 96;        // (NQKV/32, DMODEL/32)
        int tx = tid & 31, ty = tid >> 5;
        int r0 = by * 32, c0 = bx * 32;
#pragma unroll
        for (int i = 0; i < 4; i++)
            t[ty + i*8][tx] = w_qkv[(size_t)(r0 + ty + i*8) * NQKV + (c0 + tx)];
        __syncthreads();
#pragma unroll
        for (int i = 0; i < 4; i++) {
            int c = c0 + ty + i*8;
            int h = c / 192, f = c % 192;
            int cperm = ((f >> 6) << 10) + (h << 6) + (f & 63);
            wqkT[(size_t)cperm * DMODEL + (r0 + tx)] = (bf16)t[tx][ty + i*8];
        }
    } else {
        int lb = bid - 7168;
        int bx = lb & 31, by = lb >> 5;        // (DMODEL/32, DMODEL/32)
        int tx = tid & 31, ty = tid >> 5;
        int r0 = by * 32, c0 = bx * 32;
#pragma unroll
        for (int i = 0; i < 4; i++)
            t[ty + i*8][tx] = w_out[(size_t)(r0 + ty + i*8) * DMODEL + (c0 + tx)];
        __syncthreads();
#pragma unroll
        for (int i = 0; i < 4; i++)
            woT[(size_t)(c0 + ty + i*8) * DMODEL + (r0 + tx)] = (bf16)t[tx][ty + i*8];
    }
}

// ---------------- GEMM1: 256x192 tile, BK=64, 512 thr, counted-vmcnt (R16) ----
#define G1_NT 16   // 1024/64 K-tiles

__global__ __launch_bounds__(512, 2) void k_gemm_qkv(
        const bf16* __restrict__ A, const bf16* __restrict__ Bt,
        const float* __restrict__ bias,
        bf16* __restrict__ Q, bf16* __restrict__ Kp, bf16* __restrict__ Vt) {
    __shared__ __align__(16) bf16 As[2][256*64];
    __shared__ __align__(16) bf16 Bs[2][192*64];
    int tid = threadIdx.x;
    int wid = tid >> 6, lane = tid & 63;
    int wr = wid >> 2, wc = wid & 3;
    int g = lane >> 4, r = lane & 15;

    int lid = blockIdx.y * 16 + blockIdx.x;
    int swz = (lid & 7) * 32 + (lid >> 3);
    int tile_n = (swz % 16) * 192, tile_m = (swz / 16) * 256;

    f32x4 acc[8][3];
#pragma unroll
    for (int m = 0; m < 8; m++)
#pragma unroll
        for (int n = 0; n < 3; n++)
            acc[m][n] = (f32x4){0.f, 0.f, 0.f, 0.f};

    int srowA[4], schkA[4], srowB[3], schkB[3];
#pragma unroll
    for (int j2 = 0; j2 < 4; j2++) {
        int idx = tid + j2 * 512;
        srowA[j2] = idx >> 3;
        schkA[j2] = ((idx & 7) ^ (srowA[j2] & 7)) * 8;
    }
#pragma unroll
    for (int j2 = 0; j2 < 3; j2++) {
        int idx = tid + j2 * 512;
        srowB[j2] = idx >> 3;
        schkB[j2] = ((idx & 7) ^ (srowB[j2] & 7)) * 8;
    }

#define G1_STAGE(buf, k0)                                                          \
    {                                                                              \
        _Pragma("unroll")                                                          \
        for (int j2 = 0; j2 < 4; j2++)                                             \
            gload_lds16(A + (size_t)(tile_m + srowA[j2]) * DMODEL + (k0) + schkA[j2], \
                        As[buf] + (tid + j2*512) * 8);                             \
        _Pragma("unroll")                                                          \
        for (int j2 = 0; j2 < 3; j2++)                                             \
            gload_lds16(Bt + (size_t)(tile_n + srowB[j2]) * DMODEL + (k0) + schkB[j2], \
                        Bs[buf] + (tid + j2*512) * 8);                             \
    }

    G1_STAGE(0, 0);

    int r7 = r & 7;
    for (int t = 0; t < G1_NT; t++) {
        int cur = t & 1;
        if (t + 1 < G1_NT) {
            G1_STAGE(cur ^ 1, (t + 1) * 64);
            asm volatile("s_waitcnt vmcnt(7)" ::: "memory");
        } else {
            asm volatile("s_waitcnt vmcnt(0)" ::: "memory");
        }
        __builtin_amdgcn_s_barrier();
        __builtin_amdgcn_sched_barrier(0);

        const bf16* pa = As[cur];
        const bf16* pb = Bs[cur];
#pragma unroll
        for (int kk = 0; kk < 2; kk++) {
            int rchk = ((kk*4 + g) ^ r7) * 8;
            bf16x8 bfr[3];
#pragma unroll
            for (int n = 0; n < 3; n++)
                bfr[n] = ld_b8(pb + (wc*48 + n*16 + r) * 64 + rchk);
#pragma unroll
            for (int m = 0; m < 8; m++) {
                bf16x8 af = ld_b8(pa + (wr*128 + m*16 + r) * 64 + rchk);
#pragma unroll
                for (int n = 0; n < 3; n++)
                    acc[m][n] = __builtin_amdgcn_mfma_f32_16x16x32_bf16(af, bfr[n], acc[m][n], 0, 0, 0);
            }
        }
        asm volatile("s_waitcnt lgkmcnt(0)" ::: "memory");
        __builtin_amdgcn_s_barrier();
    }

#pragma unroll
    for (int m = 0; m < 8; m++) {
#pragma unroll
        for (int n = 0; n < 3; n++) {
            int col = tile_n + wc*48 + n*16 + r;
            int kind = col >> 10;
            int h = (col >> 6) & 15;
            int d = col & 63;
            float bv = bias[h*192 + (kind << 6) + d];
            if (kind == 2) {
                int row0 = tile_m + wr*128 + m*16 + g*4;
                int b = row0 >> 11, s0 = row0 & 2047;
                ushort4 vv;
                vv.x = __builtin_bit_cast(unsigned short, (bf16)(acc[m][n][0] + bv));
                vv.y = __builtin_bit_cast(unsigned short, (bf16)(acc[m][n][1] + bv));
                vv.z = __builtin_bit_cast(unsigned short, (bf16)(acc[m][n][2] + bv));
                vv.w = __builtin_bit_cast(unsigned short, (bf16)(acc[m][n][3] + bv));
                *(ushort4*)&Vt[(((size_t)(b*NH + h)) * DHEAD + d) * SEQ + s0] = vv;
            } else {
#pragma unroll
                for (int j = 0; j < 4; j++) {
                    int row = tile_m + wr*128 + m*16 + g*4 + j;
                    int b = row >> 11, s = row & 2047;
                    float v = acc[m][n][j] + bv;
                    size_t addr = (((size_t)(b*NH + h)) * SEQ + s) * DHEAD + d;
                    if (kind == 0) Q[addr]  = (bf16)(v * QSCALE);
                    else           Kp[addr] = (bf16)v;
                }
            }
        }
    }
#undef G1_STAGE
}

// ---- gemm_out: 64x128 tile, dbuf + counted vmcnt, grid 512 = 2/CU (R15) ----
__global__ __launch_bounds__(256) void k_gemm_out(
        const bf16* __restrict__ A, const bf16* __restrict__ Bt,
        const float* __restrict__ bias, float* __restrict__ out) {
    __shared__ __align__(16) bf16 As[2][64*32];
    __shared__ __align__(16) bf16 Bs[2][128*32];
    int tid = threadIdx.x;
    int wave = tid >> 6, lane = tid & 63;
    int g = lane >> 4, r = lane & 15;
    int srow = lane >> 2, schunk = (lane & 3) * 8;
    int tile_m = blockIdx.y * 64, tile_n = blockIdx.x * 128;

    f32x4 acc[4][2];
#pragma unroll
    for (int m = 0; m < 4; m++)
#pragma unroll
        for (int n = 0; n < 2; n++)
            acc[m][n] = (f32x4){0.f, 0.f, 0.f, 0.f};

#define GO_STAGE(buf, k0)                                                                 \
    {                                                                                     \
        gload_lds16(A  + (size_t)(tile_m + wave*16 + srow) * DMODEL + (k0) + schunk,      \
                    As[buf] + wave*512);                                                  \
        gload_lds16(Bt + (size_t)(tile_n + wave*16 + srow) * DMODEL + (k0) + schunk,      \
                    Bs[buf] + wave*512);                                                  \
        gload_lds16(Bt + (size_t)(tile_n + 64 + wave*16 + srow) * DMODEL + (k0) + schunk, \
                    Bs[buf] + 2048 + wave*512);                                           \
    }

    GO_STAGE(0, 0);

    for (int t = 0; t < 32; t++) {
        int cur = t & 1;
        if (t + 1 < 32) {
            GO_STAGE(cur ^ 1, (t + 1) * 32);
            asm volatile("s_waitcnt vmcnt(3)" ::: "memory");
        } else {
            asm volatile("s_waitcnt vmcnt(0)" ::: "memory");
        }
        __builtin_amdgcn_s_barrier();
        __builtin_amdgcn_sched_barrier(0);

        bf16x8 af[4], bfr[2];
#pragma unroll
        for (int m = 0; m < 4; m++) af[m]  = *(const bf16x8*)(As[cur] + (m*16 + r)*32 + g*8);
#pragma unroll
        for (int n = 0; n < 2; n++) bfr[n] = *(const bf16x8*)(Bs[cur] + (wave*32 + n*16 + r)*32 + g*8);
#pragma unroll
        for (int m = 0; m < 4; m++)
#pragma unroll
            for (int n = 0; n < 2; n++)
                acc[m][n] = __builtin_amdgcn_mfma_f32_16x16x32_bf16(af[m], bfr[n], acc[m][n], 0, 0, 0);
        asm volatile("s_waitcnt lgkmcnt(0)" ::: "memory");
        __builtin_amdgcn_s_barrier();
    }
#undef GO_STAGE

#pragma unroll
    for (int m = 0; m < 4; m++) {
#pragma unroll
        for (int n = 0; n < 2; n++) {
            int col = tile_n + wave*32 + n*16 + r;
            float bv = bias[col];
#pragma unroll
            for (int j = 0; j < 4; j++) {
                int row = tile_m + m*16 + g*4 + j;
                out[(size_t)row * DMODEL + col] = acc[m][n][j] + bv;
            }
        }
    }
}

// ---------------- flash attention: R12 structure, pad-72 LDS (0-conflict) ----
#define QBLK 128
#define KVB 64

static __device__ __forceinline__ void attn_tile_body(
        const bf16* Ks, const bf16* VsT,
        const bf16x8 qa2[4], const bf16x8& ones,
        f32x16 o32[2], f32x16& acc_l,
        int kv0, int qb, int qrow, int l31, int hi, int lane) {
    const f32x16 z16 = {0,0,0,0,0,0,0,0,0,0,0,0,0,0,0,0};
    f32x16 st[2];
    st[0] = z16; st[1] = z16;
    __builtin_amdgcn_s_setprio(1);
#pragma unroll
    for (int rb = 0; rb < 2; rb++) {
#pragma unroll
        for (int c = 0; c < 4; c++) {
            bf16x8 kf = ld_b8(Ks + (rb*32 + l31)*KSTR + c*16 + hi*8);
            st[rb] = __builtin_amdgcn_mfma_f32_32x32x16_bf16(kf, qa2[c], st[rb], 0, 0, 0);
        }
    }
    __builtin_amdgcn_s_setprio(0);

    bf16x8 vf[2][4];
#pragma unroll
    for (int dblk = 0; dblk < 2; dblk++)
#pragma unroll
        for (int c = 0; c < 4; c++)
            vf[dblk][c] = ld_b8(VsT + (dblk*32 + l31)*KSTR + c*16 + hi*8);

    bool needm = (kv0 + KVB - 1) > qb;
#pragma unroll
    for (int rb = 0; rb < 2; rb++) {
#pragma unroll
        for (int reg = 0; reg < 16; reg++) {
            float e = __builtin_amdgcn_exp2f(st[rb][reg]);
            if (needm) {
                int kv = kv0 + rb*32 + (reg & 3) + 8*(reg >> 2) + 4*hi;
                if (kv > qrow) e = 0.f;
            }
            st[rb][reg] = e;
        }
    }

    bf16x8 pa[4];
#pragma unroll
    for (int c = 0; c < 4; c++) {
        const f32x16& pp = st[c >> 1];
        const int base = (c & 1) * 8;
        uint32_t a0 = pk_bf16(pp[base+0], pp[base+1]);
        uint32_t a1 = pk_bf16(pp[base+2], pp[base+3]);
        uint32_t b0 = pk_bf16(pp[base+4], pp[base+5]);
        uint32_t b1 = pk_bf16(pp[base+6], pp[base+7]);
        u32x2 s0 = lane_swap32(a0, b0, lane);
        u32x2 s1 = lane_swap32(a1, b1, lane);
        uint4 fr = {s0.x, s1.x, s0.y, s1.y};
        pa[c] = __builtin_bit_cast(bf16x8, fr);
    }

    __builtin_amdgcn_s_setprio(1);
#pragma unroll
    for (int dblk = 0; dblk < 2; dblk++)
#pragma unroll
        for (int c = 0; c < 4; c++)
            o32[dblk] = __builtin_amdgcn_mfma_f32_32x32x16_bf16(pa[c], vf[dblk][c], o32[dblk], 0, 0, 0);
#pragma unroll
    for (int c = 0; c < 4; c++)
        acc_l = __builtin_amdgcn_mfma_f32_32x32x16_bf16(pa[c], ones, acc_l, 0, 0, 0);
    __builtin_amdgcn_s_setprio(0);
}

// ---- equal-length job tables ----
__device__ const int8_t JQC[32]  = {10,10, 4, 0, 15,15, 3, 1,  9, 9, 7, 2, 13,14, 7, 5,
                                    14,14,11, 5, 15, 8,11, 6,  8,12,12, 6, 13,13,11,12};
__device__ const int8_t JT0[32]  = { 0,11, 0, 0,  0,11, 0, 0,  0,10, 0, 0,  0, 0, 8, 0,
                                    10,20, 0, 6, 22, 0, 8, 0,  9, 0, 9, 7, 10,19,16,18};
__device__ const int8_t JT1[32]  = {11,22,10, 2, 11,22, 8, 4, 10,20, 8, 6, 10,10,16, 6,
                                    20,30, 8,12, 32, 9,16, 7, 18, 9,18,14, 19,28,24,26};
__device__ const int8_t JSEG[32] = { 0, 1, 0, 0,  0, 1, 0, 0,  0, 1, 0, 0,  0, 0, 1, 0,
                                     1, 2, 0, 1,  2, 0, 1, 0,  1, 0, 1, 1,  1, 2, 2, 2};

__global__ __launch_bounds__(256) void k_attn_split(
        const bf16* __restrict__ Q, const bf16* __restrict__ K,
        const bf16* __restrict__ Vt,
        bf16* __restrict__ Op0, bf16* __restrict__ Op1, bf16* __restrict__ Op2,
        float* __restrict__ Lp0, float* __restrict__ Lp1, float* __restrict__ Lp2) {
    int scu = blockIdx.x;
    int bh = scu >> 3, slot = scu & 7;
    int j = slot * 4 + blockIdx.y;
    int qc  = JQC[j];
    int t0  = JT0[j];
    int t1  = JT1[j];
    int seg = JSEG[j];
    int q0 = qc * QBLK;
    int tid = threadIdx.x, wave = tid >> 6, lane = tid & 63;
    int l31 = lane & 31, hi = lane >> 5;

    __shared__ __align__(16) bf16 Ks[2][KVB*KSTR];
    __shared__ __align__(16) bf16 VsT[2][KVB*KSTR];

    const bf16* Kg = K  + (size_t)bh * SEQ * DHEAD;
    const bf16* Vg = Vt + (size_t)bh * DHEAD * SEQ;

    int qb = q0 + wave * 32;
    int qrow = qb + l31;

    const bf16* qrow_p = Q + ((size_t)bh * SEQ + qrow) * DHEAD;
    bf16x8 qa2[4];
#pragma unroll
    for (int c = 0; c < 4; c++) qa2[c] = ld_b8(qrow_p + c*16 + hi*8);

    bf16x8 ones;
#pragma unroll
    for (int c = 0; c < 8; c++) ones[c] = (bf16)1.0f;

    const f32x16 z16 = {0,0,0,0,0,0,0,0,0,0,0,0,0,0,0,0};
    f32x16 o32[2], acc_l;
    o32[0] = z16; o32[1] = z16; acc_l = z16;

    int qmax_wave = qb + 31;

    int srow = tid >> 3, sc8 = (tid & 7) * 8;
    int wK0 = srow*KSTR + sc8;
    int wK1 = (srow+32)*KSTR + sc8;

    bf16x8 kreg[2], vreg[2];
    {
        int kvs = t0 * KVB;
        kreg[0] = ld_b8(Kg + (size_t)(kvs + srow)      * DHEAD + sc8);
        kreg[1] = ld_b8(Kg + (size_t)(kvs + srow + 32) * DHEAD + sc8);
        vreg[0] = ld_b8(Vg + (size_t)srow      * SEQ + kvs + sc8);
        vreg[1] = ld_b8(Vg + (size_t)(srow+32) * SEQ + kvs + sc8);
    }

    int cur = 0;
    for (int t = t0; t < t1; t++) {
        int kv0 = t * KVB;
        *(uint4*)&Ks[cur][wK0]  = __builtin_bit_cast(uint4, kreg[0]);
        *(uint4*)&Ks[cur][wK1]  = __builtin_bit_cast(uint4, kreg[1]);
        *(uint4*)&VsT[cur][wK0] = __builtin_bit_cast(uint4, vreg[0]);
        *(uint4*)&VsT[cur][wK1] = __builtin_bit_cast(uint4, vreg[1]);
        __syncthreads();

        if (t + 1 < t1) {
            int kv1 = kv0 + KVB;
            kreg[0] = ld_b8(Kg + (size_t)(kv1 + srow)      * DHEAD + sc8);
            kreg[1] = ld_b8(Kg + (size_t)(kv1 + srow + 32) * DHEAD + sc8);
            vreg[0] = ld_b8(Vg + (size_t)srow      * SEQ + kv1 + sc8);
            vreg[1] = ld_b8(Vg + (size_t)(srow+32) * SEQ + kv1 + sc8);
        }

        if (kv0 <= qmax_wave)
            attn_tile_body(Ks[cur], VsT[cur], qa2, ones, o32, acc_l,
                           kv0, qb, qrow, l31, hi, lane);
        cur ^= 1;
    }

    bf16* Op; float* Lp; size_t obase; int lbase;
    if (seg == 0)      { Op = Op0; Lp = Lp0; obase = ((size_t)bh*2048 + q0) * 64;          lbase = bh*2048 + q0; }
    else if (seg == 1) { Op = Op1; Lp = Lp1; obase = ((size_t)bh*1408 + (qc-5)*128) * 64;  lbase = bh*1408 + (qc-5)*128; }
    else               { Op = Op2; Lp = Lp2; obase = ((size_t)bh*640  + (qc-11)*128) * 64; lbase = bh*640  + (qc-11)*128; }

    if (l31 == 0) {
#pragma unroll
        for (int reg = 0; reg < 16; reg++) {
            int qr = (reg & 3) + 8*(reg >> 2) + 4*hi;
            Lp[lbase + wave*32 + qr] = acc_l[reg];
        }
    }

#pragma unroll
    for (int reg = 0; reg < 16; reg++) {
        int qr = (reg & 3) + 8*(reg >> 2) + 4*hi;
        size_t base = obase + (size_t)(wave*32 + qr) * 64 + l31;
        Op[base]      = (bf16)o32[0][reg];
        Op[base + 32] = (bf16)o32[1][reg];
    }
}

// ---- merge ----
__global__ __launch_bounds__(256) void k_merge(
        const bf16* __restrict__ Op0, const bf16* __restrict__ Op1,
        const bf16* __restrict__ Op2,
        const float* __restrict__ Lp0, const float* __restrict__ Lp1,
        const float* __restrict__ Lp2,
        bf16* __restrict__ Oa) {
    int g = blockIdx.x * 256 + threadIdx.x;      // 524288 total
    int dseg = g & 7;
    int s = (g >> 3) & 2047;
    int bh = g >> 14;
    int qc = s >> 7;
    int sl = s & 127;

    size_t r0 = ((size_t)bh * 2048 + s) * 64 + dseg*8;
    bf16x8 p0 = ld_b8(Op0 + r0);
    float l = Lp0[bh*2048 + s];
    float acc[8];
#pragma unroll
    for (int i = 0; i < 8; i++) acc[i] = (float)p0[i];

    if (qc >= 5) {
        size_t r1 = ((size_t)bh * 1408 + (qc-5)*128 + sl) * 64 + dseg*8;
        bf16x8 p1 = ld_b8(Op1 + r1);
        l += Lp1[bh*1408 + (qc-5)*128 + sl];
#pragma unroll
        for (int i = 0; i < 8; i++) acc[i] += (float)p1[i];
        if (qc >= 11) {
            size_t r2 = ((size_t)bh * 640 + (qc-11)*128 + sl) * 64 + dseg*8;
            bf16x8 p2 = ld_b8(Op2 + r2);
            l += Lp2[bh*640 + (qc-11)*128 + sl];
#pragma unroll
            for (int i = 0; i < 8; i++) acc[i] += (float)p2[i];
        }
    }

    float inv = 1.0f / l;
    bf16x8 r;
#pragma unroll
    for (int i = 0; i < 8; i++) r[i] = (bf16)(acc[i] * inv);
    int b = bh >> 4, h = bh & 15;
    *(uint4*)&Oa[(((size_t)b * SEQ + s) * NH + h) * DHEAD + dseg*8] =
        __builtin_bit_cast(uint4, r);
}

// ---- fallback single-pass attention for small ws ----
__global__ __launch_bounds__(256) void k_attn(
        const bf16* __restrict__ Q, const bf16* __restrict__ K,
        const bf16* __restrict__ Vt, bf16* __restrict__ O) {
    int bh = blockIdx.y;
    int qc = (bh >= 16) ? (15 - (int)blockIdx.x) : (int)blockIdx.x;
    int q0 = qc * QBLK;
    int tid = threadIdx.x, wave = tid >> 6, lane = tid & 63;
    int l31 = lane & 31, hi = lane >> 5;

    __shared__ __align__(16) bf16 Ks[2][KVB*KSTR];
    __shared__ __align__(16) bf16 VsT[2][KVB*KSTR];

    const bf16* Kg = K  + (size_t)bh * SEQ * DHEAD;
    const bf16* Vg = Vt + (size_t)bh * DHEAD * SEQ;

    int qb = q0 + wave * 32;
    int qrow = qb + l31;

    const bf16* qrow_p = Q + ((size_t)bh * SEQ + qrow) * DHEAD;
    bf16x8 qa2[4];
#pragma unroll
    for (int c = 0; c < 4; c++) qa2[c] = ld_b8(qrow_p + c*16 + hi*8);

    bf16x8 ones;
#pragma unroll
    for (int c = 0; c < 8; c++) ones[c] = (bf16)1.0f;

    const f32x16 z16 = {0,0,0,0,0,0,0,0,0,0,0,0,0,0,0,0};
    f32x16 o32[2], acc_l;
    o32[0] = z16; o32[1] = z16; acc_l = z16;

    int nt = 2*qc + 2;
    int qmax_wave = qb + 31;

    int srow = tid >> 3, sc8 = (tid & 7) * 8;
    int wK0 = srow*KSTR + sc8;
    int wK1 = (srow+32)*KSTR + sc8;

    bf16x8 kreg[2], vreg[2];
    kreg[0] = ld_b8(Kg + (size_t)srow      * DHEAD + sc8);
    kreg[1] = ld_b8(Kg + (size_t)(srow+32) * DHEAD + sc8);
    vreg[0] = ld_b8(Vg + (size_t)srow      * SEQ + sc8);
    vreg[1] = ld_b8(Vg + (size_t)(srow+32) * SEQ + sc8);

    int cur = 0;
    for (int t = 0; t < nt; t++) {
        int kv0 = t * KVB;
        *(uint4*)&Ks[cur][wK0]  = __builtin_bit_cast(uint4, kreg[0]);
        *(uint4*)&Ks[cur][wK1]  = __builtin_bit_cast(uint4, kreg[1]);
        *(uint4*)&VsT[cur][wK0] = __builtin_bit_cast(uint4, vreg[0]);
        *(uint4*)&VsT[cur][wK1] = __builtin_bit_cast(uint4, vreg[1]);
        __syncthreads();

        if (t + 1 < nt) {
            int kv1 = kv0 + KVB;
            kreg[0] = ld_b8(Kg + (size_t)(kv1 + srow)      * DHEAD + sc8);
            kreg[1] = ld_b8(Kg + (size_t)(kv1 + srow + 32) * DHEAD + sc8);
            vreg[0] = ld_b8(Vg + (size_t)srow      * SEQ + kv1 + sc8);
            vreg[1] = ld_b8(Vg + (size_t)(srow+32) * SEQ + kv1 + sc8);
        }

        if (kv0 <= qmax_wave)
            attn_tile_body(Ks[cur], VsT[cur], qa2, ones, o32, acc_l,
                           kv0, qb, qrow, l31, hi, lane);
        cur ^= 1;
    }

    int b = bh >> 4, h = bh & 15;
#pragma unroll
    for (int reg = 0; reg < 16; reg++) {
        int qr = (reg & 3) + 8*(reg >> 2) + 4*hi;
        int srow2 = q0 + wave*32 + qr;
        float linv = 1.0f / acc_l[reg];
        size_t base = (((size_t)b * SEQ + srow2) * NH + h) * DHEAD + l31;
        O[base]      = (bf16)(o32[0][reg] * linv);
        O[base + 32] = (bf16)(o32[1][reg] * linv);
    }
}

// ---------------- launch ----------------

extern "C" void kernel_launch(void* const* d_in, const int* in_sizes, int n_in,
                              void* d_out, int out_size, void* d_ws, size_t ws_size,
                              hipStream_t stream) {
    const float* x     = (const float*)d_in[0];
    const float* w_qkv = (const float*)d_in[1];
    const float* b_qkv = (const float*)d_in[2];
    const float* w_out = (const float*)d_in[3];
    const float* b_out = (const float*)d_in[4];
    float* out = (float*)d_out;

    char* ws = (char*)d_ws;
    bf16* xb   = (bf16*)(ws);                      // 8.39MB; later attn output
    bf16* wqkT = (bf16*)(ws + 8388608);            // 6.29MB (dead after GEMM1 -> Lp)
    bf16* woT  = (bf16*)(ws + 14680064);           // 2.10MB
    bf16* qb   = (bf16*)(ws + 16777216);           // 8.39MB
    bf16* kb   = (bf16*)(ws + 25165824);           // 8.39MB
    bf16* vb   = (bf16*)(ws + 33554432);           // 8.39MB (V^T layout)
    bf16* Op0  = (bf16*)(ws + 41943040);           // 8.39MB (seg0, all qc)
    bf16* Op1  = (bf16*)(ws + 50331648);           // 5.77MB (seg1, qc>=5)
    bf16* Op2  = (bf16*)(ws + 56098816);           // 2.62MB (seg2, qc>=11)
    float* Lp0 = (float*)(ws + 8388608);           // in dead wqkT region
    float* Lp1 = (float*)(ws + 8388608 + 262144);
    float* Lp2 = (float*)(ws + 8388608 + 524288);
    const size_t WS_NEED = 58720256;
    bf16* attn = xb;                               // reuse x_bf16 region

    k_prep<<<8192, 256, 0, stream>>>(x, w_qkv, w_out, xb, wqkT, woT);

    k_gemm_qkv<<<dim3(16, 16), 512, 0, stream>>>(xb, wqkT, b_qkv, qb, kb, vb);

    if (ws_size >= WS_NEED) {
        k_attn_split<<<dim3(256, 4), 256, 0, stream>>>(qb, kb, vb,
                                                       Op0, Op1, Op2, Lp0, Lp1, Lp2);
        k_merge<<<(NBS*NH*SEQ*DHEAD/8)/256, 256, 0, stream>>>(Op0, Op1, Op2,
                                                              Lp0, Lp1, Lp2, attn);
    } else {
        k_attn<<<dim3(SEQ/QBLK, NBS*NH), 256, 0, stream>>>(qb, kb, vb, attn);
    }

    k_gemm_out<<<dim3(DMODEL/128, MROWS/64), 256, 0, stream>>>(attn, woT, b_out, out);
}